// Round 13
// baseline (665.976 us; speedup 1.0000x reference)
//
#include <hip/hip_runtime.h>
#include <hip/hip_bf16.h>
#include <math.h>

// ---- problem dims ----
#define B_    16
#define E_    384
#define P_    4096
#define NW_   64
#define S_    64
#define H_    12
#define DH_   32
#define HID_  1536
#define T_    65536
#define SHIFT_ 4
#define MCH_  16384   // M-chunk rows (4 batches)

typedef unsigned short ushort_t;
typedef __attribute__((ext_vector_type(8))) __bf16 b8;
typedef __attribute__((ext_vector_type(8))) ushort_t u8v;
typedef __attribute__((ext_vector_type(4))) float f4;
typedef __attribute__((ext_vector_type(4))) unsigned u32x4;

__device__ __forceinline__ float u2f(ushort_t u){
    return __uint_as_float(((unsigned)u) << 16);
}
__device__ __forceinline__ ushort_t f2u(float f){
    union { __hip_bfloat16 h; ushort_t u; } cv;
    cv.h = __float2bfloat16(f);
    return cv.u;
}
__device__ __forceinline__ unsigned pack2(float lo, float hi){
    return (unsigned)f2u(lo) | ((unsigned)f2u(hi) << 16);
}
// fast gelu: tanh-form via sigmoid, max abs err ~3e-4 (<< bf16 ulp here).
__device__ __forceinline__ float gelu_f(float v){
    const float y2 = v * (1.5957691216057308f + 0.0713548162726f * v * v);
    return v * __builtin_amdgcn_rcpf(1.f + __expf(-y2));
}

#define MFMA(a,b,c) __builtin_amdgcn_mfma_f32_16x16x32_bf16((a),(b),(c),0,0,0)

// async global->LDS, 16B per lane (lds dest must be uniform + lane*16)
#define GL2LDS(gp, lp) \
    __builtin_amdgcn_global_load_lds((const __attribute__((address_space(1))) void*)(gp), \
                                     (__attribute__((address_space(3))) void*)(lp), 16, 0, 0)

// window-order row m -> linear row p (shift+window inverse), chunk-local
template<int PERM>
__device__ __forceinline__ int rowmap(int m){
    if (PERM == 0) return m;
    const int bl = m >> 12, wn = (m >> 6) & 63, sd = m & 63;
    const int i_ = ((wn >> 3) << 3) + (sd >> 3);
    const int j_ = ((wn & 7) << 3) + (sd & 7);
    const int d1 = (i_ + SHIFT_) & 63;
    const int d2 = (j_ + SHIFT_) & 63;
    return (bl << 12) + (d1 << 6) + d2;
}

// =====================================================================
// prep_all bodies
// =====================================================================
__device__ void wt_body(int bx, int by, int tid,
    const float* __restrict__ src, ushort_t* __restrict__ dst, int K, int N,
    float scale, const float* __restrict__ gv)
{
    __shared__ float t[32][33];
    const int k0 = bx * 32, n0 = by * 32;
    const int c = tid & 31, r = tid >> 5;
    for (int rr = r; rr < 32; rr += 8)
        t[rr][c] = src[(size_t)(k0 + rr) * N + n0 + c];
    __syncthreads();
    const float gg = (gv ? gv[k0 + c] : 1.f) * scale;
    for (int rr = r; rr < 32; rr += 8)
        dst[(size_t)(n0 + rr) * K + k0 + c] = f2u(t[c][rr] * gg);
}

__device__ void lnfold_body(int bx, int tid,
    const float* __restrict__ W, const float* __restrict__ g,
    const float* __restrict__ bt, float scale, int N,
    float* __restrict__ S1, float* __restrict__ S2)
{
    __shared__ float r1[8][32], r2[8][32];
    const int c = tid & 31, ks = tid >> 5;
    const int n = bx * 32 + c;
    float s1 = 0.f, s2 = 0.f;
#pragma unroll
    for (int i = 0; i < 48; ++i){     // K = 384 = 8*48
        const int k = ks * 48 + i;
        const float w = W[(size_t)k * N + n];
        s1 += g[k] * w;
        s2 += bt[k] * w;
    }
    r1[ks][c] = s1; r2[ks][c] = s2;
    __syncthreads();
    if (tid < 32){
        float a = 0.f, b2 = 0.f;
#pragma unroll
        for (int j = 0; j < 8; ++j){ a += r1[j][tid]; b2 += r2[j][tid]; }
        S1[bx * 32 + tid] = a * scale;
        S2[bx * 32 + tid] = b2 * scale;
    }
}

// one launch for all weight transposes + LN folds + bias concat
__global__ __launch_bounds__(256) void prep_all(
    const float* Wq, const float* Wk, const float* Wv, const float* Wo,
    const float* Wm1, const float* Wm2,
    const float* ln1_g, const float* ln1_b,
    const float* ln2_g, const float* ln2_b,
    const float* bq, const float* bk, const float* bv,
    ushort_t* Wqkvt, ushort_t* Wot, ushort_t* Wm1t, ushort_t* Wm2t,
    float* S1q, float* S2q, float* S1m, float* S2m, float* bqkv)
{
    const float qscale = 0.17677669529663687f;
    const int id = blockIdx.x, tid = threadIdx.x;
    if (id < 144)       wt_body(id % 12, id / 12, tid, Wq, Wqkvt, E_, E_, qscale, ln1_g);
    else if (id < 288){ const int l = id - 144; wt_body(l % 12, l / 12, tid, Wk, Wqkvt + 384 * E_, E_, E_, 1.f, ln1_g); }
    else if (id < 432){ const int l = id - 288; wt_body(l % 12, l / 12, tid, Wv, Wqkvt + 768 * E_, E_, E_, 1.f, ln1_g); }
    else if (id < 576){ const int l = id - 432; wt_body(l % 12, l / 12, tid, Wo, Wot, E_, E_, 1.f, nullptr); }
    else if (id < 1152){ const int l = id - 576; wt_body(l % 12, l / 12, tid, Wm1, Wm1t, E_, HID_, 1.f, ln2_g); }
    else if (id < 1728){ const int l = id - 1152; wt_body(l % 48, l / 48, tid, Wm2, Wm2t, HID_, E_, 1.f, nullptr); }
    else if (id < 1740) lnfold_body(id - 1728, tid, Wq, ln1_g, ln1_b, qscale, E_, S1q, S2q);
    else if (id < 1752) lnfold_body(id - 1740, tid, Wk, ln1_g, ln1_b, 1.f, E_, S1q + 384, S2q + 384);
    else if (id < 1764) lnfold_body(id - 1752, tid, Wv, ln1_g, ln1_b, 1.f, E_, S1q + 768, S2q + 768);
    else if (id < 1812) lnfold_body(id - 1764, tid, Wm1, ln2_g, ln2_b, 1.f, HID_, S1m, S2m);
    else {
        const int i = (id - 1812) * 256 + tid;
        if (i < 1152){
            float v;
            if (i < 384)      v = bq[i] * qscale;
            else if (i < 768) v = bk[i - 384];
            else              v = bv[i - 768];
            bqkv[i] = v;
        }
    }
}

// =====================================================================
// K1: x (B,E,P) f32 -> xt bf16 (B,P,E), + LN1 stats in WINDOW order.
// 64-p-wide tiles: 256B contiguous segments, 24 indep f4 loads/thread.
// =====================================================================
__global__ __launch_bounds__(256) void k1_ln_window(
    const float* __restrict__ x, ushort_t* __restrict__ xt,
    float* __restrict__ mu1w, float* __restrict__ rs1w)
{
    __shared__ ushort_t tile[64][E_ + 2];        // bf16, stride 386
    __shared__ float redS[4][64], redQ[4][64];
    const int b = blockIdx.y, p0 = blockIdx.x * 64, tid = threadIdx.x;

    {
        const int pq = tid & 15, e00 = tid >> 4;
        const float* xp = x + ((size_t)b * E_ + e00) * P_ + p0 + pq * 4;
        f4 v[24];
#pragma unroll
        for (int i = 0; i < 24; ++i)
            v[i] = *(const f4*)(xp + (size_t)(i * 16) * P_);
        float s0 = 0.f, s1 = 0.f, s2 = 0.f, s3 = 0.f;
        float q0 = 0.f, q1 = 0.f, q2 = 0.f, q3 = 0.f;
#pragma unroll
        for (int i = 0; i < 24; ++i){
            const int e = e00 + i * 16;
            tile[pq * 4 + 0][e] = f2u(v[i][0]);
            tile[pq * 4 + 1][e] = f2u(v[i][1]);
            tile[pq * 4 + 2][e] = f2u(v[i][2]);
            tile[pq * 4 + 3][e] = f2u(v[i][3]);
            s0 += v[i][0]; q0 += v[i][0] * v[i][0];
            s1 += v[i][1]; q1 += v[i][1] * v[i][1];
            s2 += v[i][2]; q2 += v[i][2] * v[i][2];
            s3 += v[i][3]; q3 += v[i][3] * v[i][3];
        }
        s0 += __shfl_xor(s0, 16); q0 += __shfl_xor(q0, 16);
        s1 += __shfl_xor(s1, 16); q1 += __shfl_xor(q1, 16);
        s2 += __shfl_xor(s2, 16); q2 += __shfl_xor(q2, 16);
        s3 += __shfl_xor(s3, 16); q3 += __shfl_xor(q3, 16);
        s0 += __shfl_xor(s0, 32); q0 += __shfl_xor(q0, 32);
        s1 += __shfl_xor(s1, 32); q1 += __shfl_xor(q1, 32);
        s2 += __shfl_xor(s2, 32); q2 += __shfl_xor(q2, 32);
        s3 += __shfl_xor(s3, 32); q3 += __shfl_xor(q3, 32);
        const int lane = tid & 63, wvi = tid >> 6;
        if (lane < 16){
            redS[wvi][pq * 4 + 0] = s0; redQ[wvi][pq * 4 + 0] = q0;
            redS[wvi][pq * 4 + 1] = s1; redQ[wvi][pq * 4 + 1] = q1;
            redS[wvi][pq * 4 + 2] = s2; redQ[wvi][pq * 4 + 2] = q2;
            redS[wvi][pq * 4 + 3] = s3; redQ[wvi][pq * 4 + 3] = q3;
        }
    }
    __syncthreads();
    if (tid < 64){
        const float s  = redS[0][tid] + redS[1][tid] + redS[2][tid] + redS[3][tid];
        const float ss = redQ[0][tid] + redQ[1][tid] + redQ[2][tid] + redQ[3][tid];
        const float mu = s / E_;
        const float rs = rsqrtf(ss / E_ - mu * mu + 1e-5f);
        const int p = p0 + tid;
        const int d1 = p >> 6, d2 = p & 63;
        const int i_ = (d1 + 64 - SHIFT_) & 63;
        const int j_ = (d2 + 64 - SHIFT_) & 63;
        const int wsd = ((((i_ >> 3) << 3) + (j_ >> 3)) << 6)
                      + ((i_ & 7) << 3) + (j_ & 7);
        mu1w[b * P_ + wsd] = mu;
        rs1w[b * P_ + wsd] = rs;
    }

    unsigned* xtu = (unsigned*)xt;
    for (int it = 0; it < 48; ++it){
        const int idx = it * 256 + tid;
        const int pj = idx / 192, ep = idx - pj * 192;
        xtu[((size_t)b * P_ + p0 + pj) * 192 + ep] = *(const unsigned*)&tile[pj][ep * 2];
    }
}

// =====================================================================
// gemm128: C = A[M][AS] @ Bm^T + epilogue, 128x128 tiles.
// Triple-buffered LDS, counted vmcnt(4), T2 both-sides swizzle.
// MODE 0: store bf16 nt (qkv)  1: gelu, store bf16 nt (mlp1)
//      2: gelu + residual RMW  3: residual RMW + window-reverse (Wo)
//      4: gelu + residual (from resid ptr) -> TRANSPOSED f32 out (kills k4)
// =====================================================================
template<int KST, int AS, int OS, int MODE, int LNF, int PERM>
__global__ __launch_bounds__(256, 3) void gemm128(
    const ushort_t* __restrict__ A, const ushort_t* __restrict__ Bm,
    const float* __restrict__ bias, ushort_t* __restrict__ out,
    const float* __restrict__ mu, const float* __restrict__ rs,
    const float* __restrict__ S1, const float* __restrict__ S2,
    const ushort_t* __restrict__ resid)
{
    __shared__ __align__(16) ushort_t lds[24576];   // 3 x (A 4096 + B 4096)
    const int tid = threadIdx.x, lane = tid & 63, wv = tid >> 6;
    const int l15 = lane & 15, l4 = lane >> 4;
    const int wr = wv >> 1, wc = wv & 1;

    // XCD-aware bijective remap (all grids have nwg % 8 == 0)
    const int gx = gridDim.x;
    const int nwg = gx * gridDim.y;
    const int d = blockIdx.y * gx + blockIdx.x;
    const int cpx = nwg >> 3;
    const int lb = (d & 7) * cpx + (d >> 3);
    const int n0 = (lb % gx) * 128;
    const size_t m0 = (size_t)(lb / gx) * 128;

    // per-thread staging source offsets; quad pre-swizzled: q_g = kq^((row>>1)&3)
    const int kq = tid & 3;
    const int xq = kq ^ ((tid >> 3) & 3);
    size_t aoff0, aoff1, boff0, boff1;
    {
        const int r0 = (int)m0 + (tid >> 2);
        aoff0 = (size_t)rowmap<PERM>(r0) * AS + xq * 8;
        aoff1 = (size_t)rowmap<PERM>(r0 + 64) * AS + xq * 8;
        const int nr = n0 + (tid >> 2);
        boff0 = (size_t)nr * (KST * 32) + xq * 8;
        boff1 = boff0 + (size_t)64 * (KST * 32);
    }

#define STG(cur, k0) do { \
        ushort_t* dst_ = lds + (cur) * 8192; \
        GL2LDS(A + aoff0 + (k0), dst_ + tid * 8); \
        GL2LDS(A + aoff1 + (k0), dst_ + (256 + tid) * 8); \
        GL2LDS(Bm + boff0 + (k0), dst_ + 4096 + tid * 8); \
        GL2LDS(Bm + boff1 + (k0), dst_ + 4096 + (256 + tid) * 8); \
    } while (0)

    f4 acc[4][4];
#pragma unroll
    for (int i = 0; i < 4; ++i)
#pragma unroll
        for (int j = 0; j < 4; ++j) acc[i][j] = (f4){0.f, 0.f, 0.f, 0.f};

    const int rq = (l4 ^ ((l15 >> 1) & 3)) * 8;

    STG(0, 0);
    STG(1, 32);
    for (int ks = 0; ks < KST; ++ks){
        if (ks < KST - 1) asm volatile("s_waitcnt vmcnt(4)" ::: "memory");
        else              asm volatile("s_waitcnt vmcnt(0)" ::: "memory");
        __builtin_amdgcn_s_barrier();
        asm volatile("" ::: "memory");
        if (ks + 2 < KST) STG((ks + 2) % 3, (ks + 2) * 32);
        asm volatile("" ::: "memory");
        const ushort_t* Al = lds + (ks % 3) * 8192;
        const ushort_t* Bl = Al + 4096;
        b8 ax[4], aw[4];
#pragma unroll
        for (int f = 0; f < 4; ++f){
            ax[f] = *(const b8*)(Al + (wr * 64 + f * 16 + l15) * 32 + rq);
            aw[f] = *(const b8*)(Bl + (wc * 64 + f * 16 + l15) * 32 + rq);
        }
#pragma unroll
        for (int fm = 0; fm < 4; ++fm)
#pragma unroll
            for (int fn = 0; fn < 4; ++fn)
                acc[fm][fn] = MFMA(aw[fn], ax[fm], acc[fm][fn]);
    }
#undef STG

    if (MODE == 4){
        // gelu + residual (f32) -> LDS transpose [128 e][36 p] -> f32 out
        float* Tf = (float*)lds;
        float* outf = (float*)out;          // chunk base (4 batches)
#pragma unroll
        for (int rg = 0; rg < 4; ++rg){
            __syncthreads();
            if (wr == (rg >> 1)){
#pragma unroll
                for (int f2h = 0; f2h < 2; ++f2h){
                    const int fm = (rg & 1) * 2 + f2h;
                    const int m5 = f2h * 16 + l15;
                    const int grow = (int)m0 + rg * 32 + m5;
#pragma unroll
                    for (int fn = 0; fn < 4; ++fn){
                        const f4 v = acc[fm][fn];
                        const int nc = wc * 64 + fn * 16 + l4 * 4;
                        const f4 bb = *(const f4*)(bias + n0 + nc);
                        const uint2 ov = *(const uint2*)(resid + (size_t)grow * E_ + n0 + nc);
                        Tf[(nc + 0) * 36 + m5] = u2f((ushort_t)ov.x)         + gelu_f(v[0] + bb[0]);
                        Tf[(nc + 1) * 36 + m5] = u2f((ushort_t)(ov.x >> 16)) + gelu_f(v[1] + bb[1]);
                        Tf[(nc + 2) * 36 + m5] = u2f((ushort_t)ov.y)         + gelu_f(v[2] + bb[2]);
                        Tf[(nc + 3) * 36 + m5] = u2f((ushort_t)(ov.y >> 16)) + gelu_f(v[3] + bb[3]);
                    }
                }
            }
            __syncthreads();
            {
                const int e = tid >> 1, po = (tid & 1) * 16;
                const int growb = (int)m0 + rg * 32;
                const int bl = growb >> 12, p12 = (growb & 4095) + po;
                float* op = outf + ((size_t)bl * E_ + n0 + e) * P_ + p12;
                const float* tp = &Tf[e * 36 + po];
#pragma unroll
                for (int j = 0; j < 4; ++j)
                    __builtin_nontemporal_store(*(const f4*)(tp + j * 4), (f4*)(op + j * 4));
            }
        }
        return;
    }

    // epilogue via per-wave LDS bounce [32][72] -> coalesced b128
    ushort_t* bounce = lds + wv * 2304;
    const int l8r = lane >> 3, l8c = lane & 7;
#pragma unroll
    for (int hh = 0; hh < 2; ++hh){
#pragma unroll
        for (int f2 = 0; f2 < 2; ++f2){
            const int fm = hh * 2 + f2;
            float mur = 0.f, rsr = 1.f;
            if (LNF){
                const int gm = (int)m0 + wr * 64 + fm * 16 + l15;
                mur = mu[gm]; rsr = rs[gm];
            }
#pragma unroll
            for (int fn = 0; fn < 4; ++fn){
                const f4 v = acc[fm][fn];
                const int nc = n0 + wc * 64 + fn * 16 + l4 * 4;
                const f4 bb = *(const f4*)(bias + nc);
                f4 w;
                if (LNF){
                    const f4 s1 = *(const f4*)(S1 + nc);
                    const f4 s2 = *(const f4*)(S2 + nc);
#pragma unroll
                    for (int r = 0; r < 4; ++r)
                        w[r] = rsr * v[r] - rsr * mur * s1[r] + s2[r] + bb[r];
                } else {
#pragma unroll
                    for (int r = 0; r < 4; ++r) w[r] = v[r] + bb[r];
                }
                uint2 pk;
                if (MODE == 1 || MODE == 2){
                    pk.x = pack2(gelu_f(w[0]), gelu_f(w[1]));
                    pk.y = pack2(gelu_f(w[2]), gelu_f(w[3]));
                } else {
                    pk.x = pack2(w[0], w[1]);
                    pk.y = pack2(w[2], w[3]);
                }
                *(uint2*)(bounce + (f2 * 16 + l15) * 72 + fn * 16 + l4 * 4) = pk;
            }
        }
#pragma unroll
        for (int i = 0; i < 4; ++i){
            const int br = i * 8 + l8r;
            const int grow = (int)m0 + wr * 64 + hh * 32 + br;
            const b8 yv = *(const b8*)(bounce + br * 72 + l8c * 8);
            size_t orow;
            if (MODE == 3){
                orow = (size_t)rowmap<1>(grow);
            } else {
                orow = (size_t)grow;
            }
            ushort_t* px = out + orow * OS + n0 + wc * 64 + l8c * 8;
            if (MODE >= 2){
                const b8 ov = *(const b8*)px;
                union { b8 v; unsigned u[4]; } o;
#pragma unroll
                for (int j = 0; j < 4; ++j)
                    o.u[j] = pack2((float)ov[2 * j] + (float)yv[2 * j],
                                   (float)ov[2 * j + 1] + (float)yv[2 * j + 1]);
                *(b8*)px = o.v;
            } else {
                union { b8 v; u32x4 q; } t; t.v = yv;
                __builtin_nontemporal_store(t.q, (u32x4*)px);
            }
        }
    }
}

// =====================================================================
// K2b: attention core. qkv [rows][1152] chunk-local (q|k|v, q scaled),
// block = (window, batch-in-chunk, head-group of 4). z [rows][384] out.
// =====================================================================
__global__ __launch_bounds__(256) void k2b_attn(
    const ushort_t* __restrict__ qkv,
    const float* __restrict__ pb, const float* __restrict__ mk,
    ushort_t* __restrict__ z)
{
    __shared__ __align__(16) ushort_t q_lds[64 * 32];
    __shared__ __align__(16) ushort_t k_lds[64 * 32];
    __shared__ __align__(16) ushort_t vt_lds[32 * 72];
    __shared__ __align__(16) ushort_t P_lds[64 * 72];

    const int w = blockIdx.x, bl = blockIdx.y, hz = blockIdx.z;
    const int tid = threadIdx.x, lane = tid & 63, wv = tid >> 6;
    const int l15 = lane & 15, l4 = lane >> 4;
    const int rowbase = (bl * NW_ + w) * S_;

    const int srow = tid >> 2, sqp = tid & 3;
    const int sfq = sqp ^ ((srow >> 1) & 3);
    const ushort_t* gql = qkv + (size_t)(rowbase + srow) * 1152 + sfq * 8;
    const ushort_t* gvl = qkv + (size_t)(rowbase + srow) * 1152 + 768 + sqp * 8;

    for (int hi = 0; hi < 4; ++hi){
        const int h = hz * 4 + hi;
        const int hb = h * 32;
        GL2LDS(gql + hb, q_lds + tid * 8);
        GL2LDS(gql + 384 + hb, k_lds + tid * 8);
        {
            const u8v vv = *(const u8v*)(gvl + hb);
#pragma unroll
            for (int j = 0; j < 8; ++j)
                vt_lds[(sqp * 8 + j) * 72 + srow] = vv[j];
        }
        __syncthreads();

        {
            const int qr = wv * 16 + l15;
            const int uq = qr * 4 + (l4 ^ ((qr >> 1) & 3));
            const b8 qfrag = *(const b8*)(&q_lds[uq * 8]);
            f4 sacc[4];
#pragma unroll
            for (int nt = 0; nt < 4; ++nt){
                const int kr = nt * 16 + l15;
                const int uk = kr * 4 + (l4 ^ ((kr >> 1) & 3));
                const b8 kfrag = *(const b8*)(&k_lds[uk * 8]);
                f4 c = (f4){0.f, 0.f, 0.f, 0.f};
                c = MFMA(qfrag, kfrag, c);
                const int t = nt * 16 + l15;
#pragma unroll
                for (int r = 0; r < 4; ++r){
                    const int sw = wv * 16 + l4 * 4 + r;
                    c[r] += pb[((size_t)h * S_ + sw) * S_ + t]
                          + mk[((size_t)w * S_ + sw) * S_ + t];
                }
                sacc[nt] = c;
            }
#pragma unroll
            for (int r = 0; r < 4; ++r){
                float m = fmaxf(fmaxf(sacc[0][r], sacc[1][r]),
                                fmaxf(sacc[2][r], sacc[3][r]));
                m = fmaxf(m, __shfl_xor(m, 1));
                m = fmaxf(m, __shfl_xor(m, 2));
                m = fmaxf(m, __shfl_xor(m, 4));
                m = fmaxf(m, __shfl_xor(m, 8));
                const float e0 = expf(sacc[0][r] - m), e1 = expf(sacc[1][r] - m);
                const float e2 = expf(sacc[2][r] - m), e3 = expf(sacc[3][r] - m);
                float s = e0 + e1 + e2 + e3;
                s += __shfl_xor(s, 1); s += __shfl_xor(s, 2);
                s += __shfl_xor(s, 4); s += __shfl_xor(s, 8);
                const float inv = 1.f / s;
                const int row = wv * 16 + l4 * 4 + r;
                P_lds[row * 72 +      l15] = f2u(e0 * inv);
                P_lds[row * 72 + 16 + l15] = f2u(e1 * inv);
                P_lds[row * 72 + 32 + l15] = f2u(e2 * inv);
                P_lds[row * 72 + 48 + l15] = f2u(e3 * inv);
            }
        }

        {
            f4 zacc[2];
#pragma unroll
            for (int nt = 0; nt < 2; ++nt) zacc[nt] = (f4){0.f, 0.f, 0.f, 0.f};
#pragma unroll
            for (int kb = 0; kb < 2; ++kb){
                const b8 pfrag = *(const b8*)(&P_lds[(wv * 16 + l15) * 72 + kb * 32 + l4 * 8]);
#pragma unroll
                for (int nt = 0; nt < 2; ++nt){
                    const b8 vfrag = *(const b8*)(&vt_lds[(nt * 16 + l15) * 72 + kb * 32 + l4 * 8]);
                    zacc[nt] = MFMA(pfrag, vfrag, zacc[nt]);
                }
            }
#pragma unroll
            for (int nt = 0; nt < 2; ++nt)
#pragma unroll
                for (int r = 0; r < 4; ++r){
                    const int row = wv * 16 + l4 * 4 + r;
                    z[(size_t)(rowbase + row) * E_ + hb + nt * 16 + l15] = f2u(zacc[nt][r]);
                }
        }
        __syncthreads();
    }
}

// =====================================================================
// LN2 stats only (LN2 itself folded into mlp gemm1)
// =====================================================================
__global__ __launch_bounds__(256) void ln2_stats(
    const ushort_t* __restrict__ xt, float* __restrict__ mu2, float* __restrict__ rs2)
{
    const int tid = threadIdx.x;
    const int lr = blockIdx.x * 64 + (tid >> 2), q = tid & 3;
    const ushort_t* rp = xt + (size_t)lr * E_;
    float s = 0.f, ss = 0.f;
#pragma unroll
    for (int i = 0; i < 12; ++i){
        const b8 v = *(const b8*)(rp + q * 8 + i * 32);
#pragma unroll
        for (int j = 0; j < 8; ++j){ const float f = (float)v[j]; s += f; ss += f * f; }
    }
    s += __shfl_xor(s, 1); ss += __shfl_xor(ss, 1);
    s += __shfl_xor(s, 2); ss += __shfl_xor(ss, 2);
    if (q == 0){
        const float m = s * (1.f / E_);
        mu2[lr] = m;
        rs2[lr] = rsqrtf(ss * (1.f / E_) - m * m + 1e-5f);
    }
}

// =====================================================================
// K4 (fallback when ws too small): xt bf16 -> out f32 (B,E,P)
// =====================================================================
__global__ __launch_bounds__(256) void k4_out(
    const ushort_t* __restrict__ xt, float* __restrict__ out)
{
    __shared__ float tile[32][68];
    const int b = blockIdx.z, p0 = blockIdx.x * 64, e0 = blockIdx.y * 32;
    const int tid = threadIdx.x;
    {
        const int r = tid >> 2, c = tid & 3;
        const u8v v = *(const u8v*)(xt + ((size_t)b * P_ + p0 + r) * E_ + e0 + c * 8);
#pragma unroll
        for (int j = 0; j < 8; ++j)
            tile[c * 8 + j][r] = u2f(v[j]);
    }
    __syncthreads();
    {
        const int er = tid >> 3, pc = tid & 7;
        float* op = out + ((size_t)b * E_ + e0 + er) * P_ + p0 + pc * 8;
        const f4 v0 = *(const f4*)&tile[er][pc * 8];
        const f4 v1 = *(const f4*)&tile[er][pc * 8 + 4];
        __builtin_nontemporal_store(v0, (f4*)op);
        __builtin_nontemporal_store(v1, (f4*)(op + 4));
    }
}

// =====================================================================
extern "C" void kernel_launch(void* const* d_in, const int* in_sizes, int n_in,
                              void* d_out, int out_size, void* d_ws, size_t ws_size,
                              hipStream_t stream)
{
    const float* x      = (const float*)d_in[0];
    const float* mask   = (const float*)d_in[1];
    const float* ln1_g  = (const float*)d_in[2];
    const float* ln1_b  = (const float*)d_in[3];
    const float* Wq     = (const float*)d_in[4];
    const float* bq     = (const float*)d_in[5];
    const float* Wk     = (const float*)d_in[6];
    const float* bk     = (const float*)d_in[7];
    const float* Wv     = (const float*)d_in[8];
    const float* bv     = (const float*)d_in[9];
    const float* Wo     = (const float*)d_in[10];
    const float* bo     = (const float*)d_in[11];
    const float* pos_b  = (const float*)d_in[12];
    const float* ln2_g  = (const float*)d_in[13];
    const float* ln2_b  = (const float*)d_in[14];
    const float* Wm1    = (const float*)d_in[15];
    const float* bm1    = (const float*)d_in[16];
    const float* Wm2    = (const float*)d_in[17];
    const float* bm2    = (const float*)d_in[18];

    // d_ws: xt at [0, 50.33MB). Big-ws layout adds h + Wm1t/Wm2t in d_ws
    // so the MLP can write the f32 output (which aliases d_out scratch)
    // directly from gemm2 (MODE 4) and skip k4.
    ushort_t* xt = (ushort_t*)d_ws;
    const bool bigws = ws_size >= (size_t)103022592;

    ushort_t* scratch = (ushort_t*)d_out;
    ushort_t* zb    = scratch;
    ushort_t* hbuf  = bigws ? (xt + 25165824) : scratch;   // 50.33MB region
    ushort_t* Wqkvt = scratch + 25165824;
    ushort_t* Wot   = Wqkvt + 1152 * E_;
    ushort_t* Wm1t  = bigws ? (xt + 50331648) : (Wot + E_ * E_);
    ushort_t* Wm2t  = Wm1t + E_ * HID_;
    ushort_t* qkvb  = scratch + 26935296;
    float*    bqkv  = (float*)(scratch + 45809664);   // 1152
    float*    S1q   = (float*)(scratch + 45811968);   // 1152
    float*    S2q   = (float*)(scratch + 45814272);   // 1152
    float*    S1m   = (float*)(scratch + 45816576);   // 1536
    float*    S2m   = (float*)(scratch + 45819648);   // 1536
    float*    mu1w  = (float*)(scratch + 45822720);   // 65536
    float*    rs1w  = (float*)(scratch + 45953792);   // 65536
    float*    mu2   = (float*)(scratch + 46084864);   // 65536
    float*    rs2   = (float*)(scratch + 46215936);   // 65536

    // ---- all prep in one launch ----
    prep_all<<<1817, 256, 0, stream>>>(Wq, Wk, Wv, Wo, Wm1, Wm2,
        ln1_g, ln1_b, ln2_g, ln2_b, bq, bk, bv,
        Wqkvt, Wot, Wm1t, Wm2t, S1q, S2q, S1m, S2m, bqkv);

    k1_ln_window<<<dim3(P_ / 64, B_), 256, 0, stream>>>(x, xt, mu1w, rs1w);

    // ---- attention phase: 4 chunks of 4 batches ----
    for (int mc = 0; mc < 4; ++mc){
        ushort_t* xtc = xt + (size_t)mc * MCH_ * E_;
        gemm128<12, E_, 1152, 0, 1, 1><<<dim3(9, MCH_ / 128), 256, 0, stream>>>(
            xtc, Wqkvt, bqkv, qkvb, mu1w + (size_t)mc * MCH_, rs1w + (size_t)mc * MCH_,
            S1q, S2q, nullptr);
        k2b_attn<<<dim3(NW_, 4, 3), 256, 0, stream>>>(qkvb, pos_b, mask, zb);
        gemm128<12, E_, E_, 3, 0, 0><<<dim3(3, MCH_ / 128), 256, 0, stream>>>(
            zb, Wot, bo, xtc, nullptr, nullptr, nullptr, nullptr, nullptr);
    }

    // ---- MLP phase (unfused; fused variants measured slower r9-r11) ----
    ln2_stats<<<T_ / 64, 256, 0, stream>>>(xt, mu2, rs2);
    for (int mc = 0; mc < 4; ++mc){
        ushort_t* xtc = xt + (size_t)mc * MCH_ * E_;
        gemm128<12, E_, HID_, 1, 1, 0><<<dim3(HID_ / 128, MCH_ / 128), 256, 0, stream>>>(
            xtc, Wm1t, bm1, hbuf, mu2 + (size_t)mc * MCH_, rs2 + (size_t)mc * MCH_,
            S1m, S2m, nullptr);
        if (bigws){
            // gemm2 writes the f32 transposed output chunk directly (MODE 4).
            // out chunk aliases d_out scratch whose consumers have all run.
            ushort_t* outc = (ushort_t*)((float*)d_out + (size_t)(mc * 4) * E_ * P_);
            gemm128<48, HID_, E_, 4, 0, 0><<<dim3(E_ / 128, MCH_ / 128), 256, 0, stream>>>(
                hbuf, Wm2t, bm2, outc, nullptr, nullptr, nullptr, nullptr, xtc);
        } else {
            gemm128<48, HID_, E_, 2, 0, 0><<<dim3(E_ / 128, MCH_ / 128), 256, 0, stream>>>(
                hbuf, Wm2t, bm2, xtc, nullptr, nullptr, nullptr, nullptr, nullptr);
        }
    }

    if (!bigws)
        k4_out<<<dim3(P_ / 64, E_ / 32, B_), 256, 0, stream>>>(xt, (float*)d_out);
}

// Round 14
// 627.913 us; speedup vs baseline: 1.0606x; 1.0606x over previous
//
#include <hip/hip_runtime.h>
#include <hip/hip_bf16.h>
#include <math.h>

// ---- problem dims ----
#define B_    16
#define E_    384
#define P_    4096
#define NW_   64
#define S_    64
#define H_    12
#define DH_   32
#define HID_  1536
#define T_    65536
#define SHIFT_ 4
#define MCH_  16384   // M-chunk rows (4 batches)

typedef unsigned short ushort_t;
typedef __attribute__((ext_vector_type(8))) __bf16 b8;
typedef __attribute__((ext_vector_type(8))) ushort_t u8v;
typedef __attribute__((ext_vector_type(4))) float f4;
typedef __attribute__((ext_vector_type(4))) unsigned u32x4;

__device__ __forceinline__ float u2f(ushort_t u){
    return __uint_as_float(((unsigned)u) << 16);
}
__device__ __forceinline__ ushort_t f2u(float f){
    union { __hip_bfloat16 h; ushort_t u; } cv;
    cv.h = __float2bfloat16(f);
    return cv.u;
}
__device__ __forceinline__ unsigned pack2(float lo, float hi){
    return (unsigned)f2u(lo) | ((unsigned)f2u(hi) << 16);
}
// fast gelu: tanh-form via sigmoid, max abs err ~3e-4 (<< bf16 ulp here).
__device__ __forceinline__ float gelu_f(float v){
    const float y2 = v * (1.5957691216057308f + 0.0713548162726f * v * v);
    return v * __builtin_amdgcn_rcpf(1.f + __expf(-y2));
}

#define MFMA(a,b,c) __builtin_amdgcn_mfma_f32_16x16x32_bf16((a),(b),(c),0,0,0)

// async global->LDS, 16B per lane (lds dest must be uniform + lane*16)
#define GL2LDS(gp, lp) \
    __builtin_amdgcn_global_load_lds((const __attribute__((address_space(1))) void*)(gp), \
                                     (__attribute__((address_space(3))) void*)(lp), 16, 0, 0)

// window-order row m -> linear row p (shift+window inverse), chunk-local
template<int PERM>
__device__ __forceinline__ int rowmap(int m){
    if (PERM == 0) return m;
    const int bl = m >> 12, wn = (m >> 6) & 63, sd = m & 63;
    const int i_ = ((wn >> 3) << 3) + (sd >> 3);
    const int j_ = ((wn & 7) << 3) + (sd & 7);
    const int d1 = (i_ + SHIFT_) & 63;
    const int d2 = (j_ + SHIFT_) & 63;
    return (bl << 12) + (d1 << 6) + d2;
}

// =====================================================================
// prep_all bodies
// =====================================================================
__device__ void wt_body(int bx, int by, int tid,
    const float* __restrict__ src, ushort_t* __restrict__ dst, int K, int N,
    float scale, const float* __restrict__ gv)
{
    __shared__ float t[32][33];
    const int k0 = bx * 32, n0 = by * 32;
    const int c = tid & 31, r = tid >> 5;
    for (int rr = r; rr < 32; rr += 8)
        t[rr][c] = src[(size_t)(k0 + rr) * N + n0 + c];
    __syncthreads();
    const float gg = (gv ? gv[k0 + c] : 1.f) * scale;
    for (int rr = r; rr < 32; rr += 8)
        dst[(size_t)(n0 + rr) * K + k0 + c] = f2u(t[c][rr] * gg);
}

__device__ void lnfold_body(int bx, int tid,
    const float* __restrict__ W, const float* __restrict__ g,
    const float* __restrict__ bt, float scale, int N,
    float* __restrict__ S1, float* __restrict__ S2)
{
    __shared__ float r1[8][32], r2[8][32];
    const int c = tid & 31, ks = tid >> 5;
    const int n = bx * 32 + c;
    float s1 = 0.f, s2 = 0.f;
#pragma unroll
    for (int i = 0; i < 48; ++i){     // K = 384 = 8*48
        const int k = ks * 48 + i;
        const float w = W[(size_t)k * N + n];
        s1 += g[k] * w;
        s2 += bt[k] * w;
    }
    r1[ks][c] = s1; r2[ks][c] = s2;
    __syncthreads();
    if (tid < 32){
        float a = 0.f, b2 = 0.f;
#pragma unroll
        for (int j = 0; j < 8; ++j){ a += r1[j][tid]; b2 += r2[j][tid]; }
        S1[bx * 32 + tid] = a * scale;
        S2[bx * 32 + tid] = b2 * scale;
    }
}

// one launch for all weight transposes + LN folds + bias concat
__global__ __launch_bounds__(256) void prep_all(
    const float* Wq, const float* Wk, const float* Wv, const float* Wo,
    const float* Wm1, const float* Wm2,
    const float* ln1_g, const float* ln1_b,
    const float* ln2_g, const float* ln2_b,
    const float* bq, const float* bk, const float* bv,
    ushort_t* Wqkvt, ushort_t* Wot, ushort_t* Wm1t, ushort_t* Wm2t,
    float* S1q, float* S2q, float* S1m, float* S2m, float* bqkv)
{
    const float qscale = 0.17677669529663687f;
    const int id = blockIdx.x, tid = threadIdx.x;
    if (id < 144)       wt_body(id % 12, id / 12, tid, Wq, Wqkvt, E_, E_, qscale, ln1_g);
    else if (id < 288){ const int l = id - 144; wt_body(l % 12, l / 12, tid, Wk, Wqkvt + 384 * E_, E_, E_, 1.f, ln1_g); }
    else if (id < 432){ const int l = id - 288; wt_body(l % 12, l / 12, tid, Wv, Wqkvt + 768 * E_, E_, E_, 1.f, ln1_g); }
    else if (id < 576){ const int l = id - 432; wt_body(l % 12, l / 12, tid, Wo, Wot, E_, E_, 1.f, nullptr); }
    else if (id < 1152){ const int l = id - 576; wt_body(l % 12, l / 12, tid, Wm1, Wm1t, E_, HID_, 1.f, ln2_g); }
    else if (id < 1728){ const int l = id - 1152; wt_body(l % 48, l / 48, tid, Wm2, Wm2t, HID_, E_, 1.f, nullptr); }
    else if (id < 1740) lnfold_body(id - 1728, tid, Wq, ln1_g, ln1_b, qscale, E_, S1q, S2q);
    else if (id < 1752) lnfold_body(id - 1740, tid, Wk, ln1_g, ln1_b, 1.f, E_, S1q + 384, S2q + 384);
    else if (id < 1764) lnfold_body(id - 1752, tid, Wv, ln1_g, ln1_b, 1.f, E_, S1q + 768, S2q + 768);
    else if (id < 1812) lnfold_body(id - 1764, tid, Wm1, ln2_g, ln2_b, 1.f, HID_, S1m, S2m);
    else {
        const int i = (id - 1812) * 256 + tid;
        if (i < 1152){
            float v;
            if (i < 384)      v = bq[i] * qscale;
            else if (i < 768) v = bk[i - 384];
            else              v = bv[i - 768];
            bqkv[i] = v;
        }
    }
}

// =====================================================================
// K1: x (B,E,P) f32 -> xt bf16 (B,P,E), + LN1 stats in WINDOW order.
// 64-p-wide tiles: 256B contiguous segments, 24 indep f4 loads/thread.
// =====================================================================
__global__ __launch_bounds__(256) void k1_ln_window(
    const float* __restrict__ x, ushort_t* __restrict__ xt,
    float* __restrict__ mu1w, float* __restrict__ rs1w)
{
    __shared__ ushort_t tile[64][E_ + 2];        // bf16, stride 386
    __shared__ float redS[4][64], redQ[4][64];
    const int b = blockIdx.y, p0 = blockIdx.x * 64, tid = threadIdx.x;

    {
        const int pq = tid & 15, e00 = tid >> 4;
        const float* xp = x + ((size_t)b * E_ + e00) * P_ + p0 + pq * 4;
        f4 v[24];
#pragma unroll
        for (int i = 0; i < 24; ++i)
            v[i] = *(const f4*)(xp + (size_t)(i * 16) * P_);
        float s0 = 0.f, s1 = 0.f, s2 = 0.f, s3 = 0.f;
        float q0 = 0.f, q1 = 0.f, q2 = 0.f, q3 = 0.f;
#pragma unroll
        for (int i = 0; i < 24; ++i){
            const int e = e00 + i * 16;
            tile[pq * 4 + 0][e] = f2u(v[i][0]);
            tile[pq * 4 + 1][e] = f2u(v[i][1]);
            tile[pq * 4 + 2][e] = f2u(v[i][2]);
            tile[pq * 4 + 3][e] = f2u(v[i][3]);
            s0 += v[i][0]; q0 += v[i][0] * v[i][0];
            s1 += v[i][1]; q1 += v[i][1] * v[i][1];
            s2 += v[i][2]; q2 += v[i][2] * v[i][2];
            s3 += v[i][3]; q3 += v[i][3] * v[i][3];
        }
        s0 += __shfl_xor(s0, 16); q0 += __shfl_xor(q0, 16);
        s1 += __shfl_xor(s1, 16); q1 += __shfl_xor(q1, 16);
        s2 += __shfl_xor(s2, 16); q2 += __shfl_xor(q2, 16);
        s3 += __shfl_xor(s3, 16); q3 += __shfl_xor(q3, 16);
        s0 += __shfl_xor(s0, 32); q0 += __shfl_xor(q0, 32);
        s1 += __shfl_xor(s1, 32); q1 += __shfl_xor(q1, 32);
        s2 += __shfl_xor(s2, 32); q2 += __shfl_xor(q2, 32);
        s3 += __shfl_xor(s3, 32); q3 += __shfl_xor(q3, 32);
        const int lane = tid & 63, wvi = tid >> 6;
        if (lane < 16){
            redS[wvi][pq * 4 + 0] = s0; redQ[wvi][pq * 4 + 0] = q0;
            redS[wvi][pq * 4 + 1] = s1; redQ[wvi][pq * 4 + 1] = q1;
            redS[wvi][pq * 4 + 2] = s2; redQ[wvi][pq * 4 + 2] = q2;
            redS[wvi][pq * 4 + 3] = s3; redQ[wvi][pq * 4 + 3] = q3;
        }
    }
    __syncthreads();
    if (tid < 64){
        const float s  = redS[0][tid] + redS[1][tid] + redS[2][tid] + redS[3][tid];
        const float ss = redQ[0][tid] + redQ[1][tid] + redQ[2][tid] + redQ[3][tid];
        const float mu = s / E_;
        const float rs = rsqrtf(ss / E_ - mu * mu + 1e-5f);
        const int p = p0 + tid;
        const int d1 = p >> 6, d2 = p & 63;
        const int i_ = (d1 + 64 - SHIFT_) & 63;
        const int j_ = (d2 + 64 - SHIFT_) & 63;
        const int wsd = ((((i_ >> 3) << 3) + (j_ >> 3)) << 6)
                      + ((i_ & 7) << 3) + (j_ & 7);
        mu1w[b * P_ + wsd] = mu;
        rs1w[b * P_ + wsd] = rs;
    }

    unsigned* xtu = (unsigned*)xt;
    for (int it = 0; it < 48; ++it){
        const int idx = it * 256 + tid;
        const int pj = idx / 192, ep = idx - pj * 192;
        xtu[((size_t)b * P_ + p0 + pj) * 192 + ep] = *(const unsigned*)&tile[pj][ep * 2];
    }
}

// =====================================================================
// gemm128: C = A[M][AS] @ Bm^T + epilogue, 128x128 tiles.
// Triple-buffered LDS, counted vmcnt(4), T2 both-sides swizzle.
// MODE 0: store bf16 nt (qkv)  1: gelu, store bf16 nt (mlp1)
//      2: gelu + residual RMW  3: residual RMW + window-reverse (Wo)
//      4: gelu + residual (resid ptr) -> TRANSPOSED f32 out (kills k4).
//         Store phase: 4 lanes cover 128B contiguous p-range of one
//         e-row per instruction (r13 lesson: lane-scattered 16B NT
//         stores -> 2.85x HBM write amplification).
// =====================================================================
template<int KST, int AS, int OS, int MODE, int LNF, int PERM>
__global__ __launch_bounds__(256, 3) void gemm128(
    const ushort_t* __restrict__ A, const ushort_t* __restrict__ Bm,
    const float* __restrict__ bias, ushort_t* __restrict__ out,
    const float* __restrict__ mu, const float* __restrict__ rs,
    const float* __restrict__ S1, const float* __restrict__ S2,
    const ushort_t* __restrict__ resid)
{
    __shared__ __align__(16) ushort_t lds[24576];   // 3 x (A 4096 + B 4096)
    const int tid = threadIdx.x, lane = tid & 63, wv = tid >> 6;
    const int l15 = lane & 15, l4 = lane >> 4;
    const int wr = wv >> 1, wc = wv & 1;

    // XCD-aware bijective remap (all grids have nwg % 8 == 0)
    const int gx = gridDim.x;
    const int nwg = gx * gridDim.y;
    const int d = blockIdx.y * gx + blockIdx.x;
    const int cpx = nwg >> 3;
    const int lb = (d & 7) * cpx + (d >> 3);
    const int n0 = (lb % gx) * 128;
    const size_t m0 = (size_t)(lb / gx) * 128;

    // per-thread staging source offsets; quad pre-swizzled: q_g = kq^((row>>1)&3)
    const int kq = tid & 3;
    const int xq = kq ^ ((tid >> 3) & 3);
    size_t aoff0, aoff1, boff0, boff1;
    {
        const int r0 = (int)m0 + (tid >> 2);
        aoff0 = (size_t)rowmap<PERM>(r0) * AS + xq * 8;
        aoff1 = (size_t)rowmap<PERM>(r0 + 64) * AS + xq * 8;
        const int nr = n0 + (tid >> 2);
        boff0 = (size_t)nr * (KST * 32) + xq * 8;
        boff1 = boff0 + (size_t)64 * (KST * 32);
    }

#define STG(cur, k0) do { \
        ushort_t* dst_ = lds + (cur) * 8192; \
        GL2LDS(A + aoff0 + (k0), dst_ + tid * 8); \
        GL2LDS(A + aoff1 + (k0), dst_ + (256 + tid) * 8); \
        GL2LDS(Bm + boff0 + (k0), dst_ + 4096 + tid * 8); \
        GL2LDS(Bm + boff1 + (k0), dst_ + 4096 + (256 + tid) * 8); \
    } while (0)

    f4 acc[4][4];
#pragma unroll
    for (int i = 0; i < 4; ++i)
#pragma unroll
        for (int j = 0; j < 4; ++j) acc[i][j] = (f4){0.f, 0.f, 0.f, 0.f};

    const int rq = (l4 ^ ((l15 >> 1) & 3)) * 8;

    STG(0, 0);
    STG(1, 32);
    for (int ks = 0; ks < KST; ++ks){
        if (ks < KST - 1) asm volatile("s_waitcnt vmcnt(4)" ::: "memory");
        else              asm volatile("s_waitcnt vmcnt(0)" ::: "memory");
        __builtin_amdgcn_s_barrier();
        asm volatile("" ::: "memory");
        if (ks + 2 < KST) STG((ks + 2) % 3, (ks + 2) * 32);
        asm volatile("" ::: "memory");
        const ushort_t* Al = lds + (ks % 3) * 8192;
        const ushort_t* Bl = Al + 4096;
        b8 ax[4], aw[4];
#pragma unroll
        for (int f = 0; f < 4; ++f){
            ax[f] = *(const b8*)(Al + (wr * 64 + f * 16 + l15) * 32 + rq);
            aw[f] = *(const b8*)(Bl + (wc * 64 + f * 16 + l15) * 32 + rq);
        }
#pragma unroll
        for (int fm = 0; fm < 4; ++fm)
#pragma unroll
            for (int fn = 0; fn < 4; ++fn)
                acc[fm][fn] = MFMA(aw[fn], ax[fm], acc[fm][fn]);
    }
#undef STG

    if (MODE == 4){
        // gelu + residual (f32) -> LDS transpose [128 e][36 p] -> f32 out
        float* Tf = (float*)lds;
        float* outf = (float*)out;          // chunk base (4 batches)
#pragma unroll
        for (int rg = 0; rg < 4; ++rg){
            __syncthreads();
            if (wr == (rg >> 1)){
#pragma unroll
                for (int f2h = 0; f2h < 2; ++f2h){
                    const int fm = (rg & 1) * 2 + f2h;
                    const int m5 = f2h * 16 + l15;
                    const int grow = (int)m0 + rg * 32 + m5;
#pragma unroll
                    for (int fn = 0; fn < 4; ++fn){
                        const f4 v = acc[fm][fn];
                        const int nc = wc * 64 + fn * 16 + l4 * 4;
                        const f4 bb = *(const f4*)(bias + n0 + nc);
                        const uint2 ov = *(const uint2*)(resid + (size_t)grow * E_ + n0 + nc);
                        Tf[(nc + 0) * 36 + m5] = u2f((ushort_t)ov.x)         + gelu_f(v[0] + bb[0]);
                        Tf[(nc + 1) * 36 + m5] = u2f((ushort_t)(ov.x >> 16)) + gelu_f(v[1] + bb[1]);
                        Tf[(nc + 2) * 36 + m5] = u2f((ushort_t)ov.y)         + gelu_f(v[2] + bb[2]);
                        Tf[(nc + 3) * 36 + m5] = u2f((ushort_t)(ov.y >> 16)) + gelu_f(v[3] + bb[3]);
                    }
                }
            }
            __syncthreads();
            {
                // lane quad covers 128B contiguous p of one e-row per instr
                const int growb = (int)m0 + rg * 32;
                const int bl = growb >> 12, p12 = growb & 4095;
                const int po = (tid & 3) * 8;
#pragma unroll
                for (int eh = 0; eh < 2; ++eh){
                    const int e = eh * 64 + (tid >> 2);
                    float* op = outf + ((size_t)bl * E_ + n0 + e) * P_ + p12 + po;
                    const float* tp = &Tf[e * 36 + po];
                    __builtin_nontemporal_store(*(const f4*)tp, (f4*)op);
                    __builtin_nontemporal_store(*(const f4*)(tp + 4), (f4*)(op + 4));
                }
            }
        }
        return;
    }

    // epilogue via per-wave LDS bounce [32][72] -> coalesced b128
    ushort_t* bounce = lds + wv * 2304;
    const int l8r = lane >> 3, l8c = lane & 7;
#pragma unroll
    for (int hh = 0; hh < 2; ++hh){
#pragma unroll
        for (int f2 = 0; f2 < 2; ++f2){
            const int fm = hh * 2 + f2;
            float mur = 0.f, rsr = 1.f;
            if (LNF){
                const int gm = (int)m0 + wr * 64 + fm * 16 + l15;
                mur = mu[gm]; rsr = rs[gm];
            }
#pragma unroll
            for (int fn = 0; fn < 4; ++fn){
                const f4 v = acc[fm][fn];
                const int nc = n0 + wc * 64 + fn * 16 + l4 * 4;
                const f4 bb = *(const f4*)(bias + nc);
                f4 w;
                if (LNF){
                    const f4 s1 = *(const f4*)(S1 + nc);
                    const f4 s2 = *(const f4*)(S2 + nc);
#pragma unroll
                    for (int r = 0; r < 4; ++r)
                        w[r] = rsr * v[r] - rsr * mur * s1[r] + s2[r] + bb[r];
                } else {
#pragma unroll
                    for (int r = 0; r < 4; ++r) w[r] = v[r] + bb[r];
                }
                uint2 pk;
                if (MODE == 1 || MODE == 2){
                    pk.x = pack2(gelu_f(w[0]), gelu_f(w[1]));
                    pk.y = pack2(gelu_f(w[2]), gelu_f(w[3]));
                } else {
                    pk.x = pack2(w[0], w[1]);
                    pk.y = pack2(w[2], w[3]);
                }
                *(uint2*)(bounce + (f2 * 16 + l15) * 72 + fn * 16 + l4 * 4) = pk;
            }
        }
#pragma unroll
        for (int i = 0; i < 4; ++i){
            const int br = i * 8 + l8r;
            const int grow = (int)m0 + wr * 64 + hh * 32 + br;
            const b8 yv = *(const b8*)(bounce + br * 72 + l8c * 8);
            size_t orow;
            if (MODE == 3){
                orow = (size_t)rowmap<1>(grow);
            } else {
                orow = (size_t)grow;
            }
            ushort_t* px = out + orow * OS + n0 + wc * 64 + l8c * 8;
            if (MODE >= 2){
                const b8 ov = *(const b8*)px;
                union { b8 v; unsigned u[4]; } o;
#pragma unroll
                for (int j = 0; j < 4; ++j)
                    o.u[j] = pack2((float)ov[2 * j] + (float)yv[2 * j],
                                   (float)ov[2 * j + 1] + (float)yv[2 * j + 1]);
                *(b8*)px = o.v;
            } else {
                union { b8 v; u32x4 q; } t; t.v = yv;
                __builtin_nontemporal_store(t.q, (u32x4*)px);
            }
        }
    }
}

// =====================================================================
// K2b: attention core. qkv [rows][1152] chunk-local (q|k|v, q scaled),
// block = (window, batch-in-chunk, head-group of 4). z [rows][384] out.
// =====================================================================
__global__ __launch_bounds__(256) void k2b_attn(
    const ushort_t* __restrict__ qkv,
    const float* __restrict__ pb, const float* __restrict__ mk,
    ushort_t* __restrict__ z)
{
    __shared__ __align__(16) ushort_t q_lds[64 * 32];
    __shared__ __align__(16) ushort_t k_lds[64 * 32];
    __shared__ __align__(16) ushort_t vt_lds[32 * 72];
    __shared__ __align__(16) ushort_t P_lds[64 * 72];

    const int w = blockIdx.x, bl = blockIdx.y, hz = blockIdx.z;
    const int tid = threadIdx.x, lane = tid & 63, wv = tid >> 6;
    const int l15 = lane & 15, l4 = lane >> 4;
    const int rowbase = (bl * NW_ + w) * S_;

    const int srow = tid >> 2, sqp = tid & 3;
    const int sfq = sqp ^ ((srow >> 1) & 3);
    const ushort_t* gql = qkv + (size_t)(rowbase + srow) * 1152 + sfq * 8;
    const ushort_t* gvl = qkv + (size_t)(rowbase + srow) * 1152 + 768 + sqp * 8;

    for (int hi = 0; hi < 4; ++hi){
        const int h = hz * 4 + hi;
        const int hb = h * 32;
        GL2LDS(gql + hb, q_lds + tid * 8);
        GL2LDS(gql + 384 + hb, k_lds + tid * 8);
        {
            const u8v vv = *(const u8v*)(gvl + hb);
#pragma unroll
            for (int j = 0; j < 8; ++j)
                vt_lds[(sqp * 8 + j) * 72 + srow] = vv[j];
        }
        __syncthreads();

        {
            const int qr = wv * 16 + l15;
            const int uq = qr * 4 + (l4 ^ ((qr >> 1) & 3));
            const b8 qfrag = *(const b8*)(&q_lds[uq * 8]);
            f4 sacc[4];
#pragma unroll
            for (int nt = 0; nt < 4; ++nt){
                const int kr = nt * 16 + l15;
                const int uk = kr * 4 + (l4 ^ ((kr >> 1) & 3));
                const b8 kfrag = *(const b8*)(&k_lds[uk * 8]);
                f4 c = (f4){0.f, 0.f, 0.f, 0.f};
                c = MFMA(qfrag, kfrag, c);
                const int t = nt * 16 + l15;
#pragma unroll
                for (int r = 0; r < 4; ++r){
                    const int sw = wv * 16 + l4 * 4 + r;
                    c[r] += pb[((size_t)h * S_ + sw) * S_ + t]
                          + mk[((size_t)w * S_ + sw) * S_ + t];
                }
                sacc[nt] = c;
            }
#pragma unroll
            for (int r = 0; r < 4; ++r){
                float m = fmaxf(fmaxf(sacc[0][r], sacc[1][r]),
                                fmaxf(sacc[2][r], sacc[3][r]));
                m = fmaxf(m, __shfl_xor(m, 1));
                m = fmaxf(m, __shfl_xor(m, 2));
                m = fmaxf(m, __shfl_xor(m, 4));
                m = fmaxf(m, __shfl_xor(m, 8));
                const float e0 = expf(sacc[0][r] - m), e1 = expf(sacc[1][r] - m);
                const float e2 = expf(sacc[2][r] - m), e3 = expf(sacc[3][r] - m);
                float s = e0 + e1 + e2 + e3;
                s += __shfl_xor(s, 1); s += __shfl_xor(s, 2);
                s += __shfl_xor(s, 4); s += __shfl_xor(s, 8);
                const float inv = 1.f / s;
                const int row = wv * 16 + l4 * 4 + r;
                P_lds[row * 72 +      l15] = f2u(e0 * inv);
                P_lds[row * 72 + 16 + l15] = f2u(e1 * inv);
                P_lds[row * 72 + 32 + l15] = f2u(e2 * inv);
                P_lds[row * 72 + 48 + l15] = f2u(e3 * inv);
            }
        }

        {
            f4 zacc[2];
#pragma unroll
            for (int nt = 0; nt < 2; ++nt) zacc[nt] = (f4){0.f, 0.f, 0.f, 0.f};
#pragma unroll
            for (int kb = 0; kb < 2; ++kb){
                const b8 pfrag = *(const b8*)(&P_lds[(wv * 16 + l15) * 72 + kb * 32 + l4 * 8]);
#pragma unroll
                for (int nt = 0; nt < 2; ++nt){
                    const b8 vfrag = *(const b8*)(&vt_lds[(nt * 16 + l15) * 72 + kb * 32 + l4 * 8]);
                    zacc[nt] = MFMA(pfrag, vfrag, zacc[nt]);
                }
            }
#pragma unroll
            for (int nt = 0; nt < 2; ++nt)
#pragma unroll
                for (int r = 0; r < 4; ++r){
                    const int row = wv * 16 + l4 * 4 + r;
                    z[(size_t)(rowbase + row) * E_ + hb + nt * 16 + l15] = f2u(zacc[nt][r]);
                }
        }
        __syncthreads();
    }
}

// =====================================================================
// LN2 stats only (LN2 itself folded into mlp gemm1)
// =====================================================================
__global__ __launch_bounds__(256) void ln2_stats(
    const ushort_t* __restrict__ xt, float* __restrict__ mu2, float* __restrict__ rs2)
{
    const int tid = threadIdx.x;
    const int lr = blockIdx.x * 64 + (tid >> 2), q = tid & 3;
    const ushort_t* rp = xt + (size_t)lr * E_;
    float s = 0.f, ss = 0.f;
#pragma unroll
    for (int i = 0; i < 12; ++i){
        const b8 v = *(const b8*)(rp + q * 8 + i * 32);
#pragma unroll
        for (int j = 0; j < 8; ++j){ const float f = (float)v[j]; s += f; ss += f * f; }
    }
    s += __shfl_xor(s, 1); ss += __shfl_xor(ss, 1);
    s += __shfl_xor(s, 2); ss += __shfl_xor(ss, 2);
    if (q == 0){
        const float m = s * (1.f / E_);
        mu2[lr] = m;
        rs2[lr] = rsqrtf(ss * (1.f / E_) - m * m + 1e-5f);
    }
}

// =====================================================================
// K4 (fallback when ws too small): xt bf16 -> out f32 (B,E,P)
// =====================================================================
__global__ __launch_bounds__(256) void k4_out(
    const ushort_t* __restrict__ xt, float* __restrict__ out)
{
    __shared__ float tile[32][68];
    const int b = blockIdx.z, p0 = blockIdx.x * 64, e0 = blockIdx.y * 32;
    const int tid = threadIdx.x;
    {
        const int r = tid >> 2, c = tid & 3;
        const u8v v = *(const u8v*)(xt + ((size_t)b * P_ + p0 + r) * E_ + e0 + c * 8);
#pragma unroll
        for (int j = 0; j < 8; ++j)
            tile[c * 8 + j][r] = u2f(v[j]);
    }
    __syncthreads();
    {
        const int er = tid >> 3, pc = tid & 7;
        float* op = out + ((size_t)b * E_ + e0 + er) * P_ + p0 + pc * 8;
        const f4 v0 = *(const f4*)&tile[er][pc * 8];
        const f4 v1 = *(const f4*)&tile[er][pc * 8 + 4];
        __builtin_nontemporal_store(v0, (f4*)op);
        __builtin_nontemporal_store(v1, (f4*)(op + 4));
    }
}

// =====================================================================
extern "C" void kernel_launch(void* const* d_in, const int* in_sizes, int n_in,
                              void* d_out, int out_size, void* d_ws, size_t ws_size,
                              hipStream_t stream)
{
    const float* x      = (const float*)d_in[0];
    const float* mask   = (const float*)d_in[1];
    const float* ln1_g  = (const float*)d_in[2];
    const float* ln1_b  = (const float*)d_in[3];
    const float* Wq     = (const float*)d_in[4];
    const float* bq     = (const float*)d_in[5];
    const float* Wk     = (const float*)d_in[6];
    const float* bk     = (const float*)d_in[7];
    const float* Wv     = (const float*)d_in[8];
    const float* bv     = (const float*)d_in[9];
    const float* Wo     = (const float*)d_in[10];
    const float* bo     = (const float*)d_in[11];
    const float* pos_b  = (const float*)d_in[12];
    const float* ln2_g  = (const float*)d_in[13];
    const float* ln2_b  = (const float*)d_in[14];
    const float* Wm1    = (const float*)d_in[15];
    const float* bm1    = (const float*)d_in[16];
    const float* Wm2    = (const float*)d_in[17];
    const float* bm2    = (const float*)d_in[18];

    // d_ws: xt at [0, 50.33MB). Big-ws layout adds h + Wm1t/Wm2t in d_ws
    // so the MLP can write the f32 output (which aliases d_out scratch)
    // directly from gemm2 (MODE 4) and skip k4.
    ushort_t* xt = (ushort_t*)d_ws;
    const bool bigws = ws_size >= (size_t)103022592;

    ushort_t* scratch = (ushort_t*)d_out;
    ushort_t* zb    = scratch;
    ushort_t* hbuf  = bigws ? (xt + 25165824) : scratch;   // 50.33MB region
    ushort_t* Wqkvt = scratch + 25165824;
    ushort_t* Wot   = Wqkvt + 1152 * E_;
    ushort_t* Wm1t  = bigws ? (xt + 50331648) : (Wot + E_ * E_);
    ushort_t* Wm2t  = Wm1t + E_ * HID_;
    ushort_t* qkvb  = scratch + 26935296;
    float*    bqkv  = (float*)(scratch + 45809664);   // 1152
    float*    S1q   = (float*)(scratch + 45811968);   // 1152
    float*    S2q   = (float*)(scratch + 45814272);   // 1152
    float*    S1m   = (float*)(scratch + 45816576);   // 1536
    float*    S2m   = (float*)(scratch + 45819648);   // 1536
    float*    mu1w  = (float*)(scratch + 45822720);   // 65536
    float*    rs1w  = (float*)(scratch + 45953792);   // 65536
    float*    mu2   = (float*)(scratch + 46084864);   // 65536
    float*    rs2   = (float*)(scratch + 46215936);   // 65536

    // ---- all prep in one launch ----
    prep_all<<<1817, 256, 0, stream>>>(Wq, Wk, Wv, Wo, Wm1, Wm2,
        ln1_g, ln1_b, ln2_g, ln2_b, bq, bk, bv,
        Wqkvt, Wot, Wm1t, Wm2t, S1q, S2q, S1m, S2m, bqkv);

    k1_ln_window<<<dim3(P_ / 64, B_), 256, 0, stream>>>(x, xt, mu1w, rs1w);

    // ---- attention phase: 4 chunks of 4 batches ----
    for (int mc = 0; mc < 4; ++mc){
        ushort_t* xtc = xt + (size_t)mc * MCH_ * E_;
        gemm128<12, E_, 1152, 0, 1, 1><<<dim3(9, MCH_ / 128), 256, 0, stream>>>(
            xtc, Wqkvt, bqkv, qkvb, mu1w + (size_t)mc * MCH_, rs1w + (size_t)mc * MCH_,
            S1q, S2q, nullptr);
        k2b_attn<<<dim3(NW_, 4, 3), 256, 0, stream>>>(qkvb, pos_b, mask, zb);
        gemm128<12, E_, E_, 3, 0, 0><<<dim3(3, MCH_ / 128), 256, 0, stream>>>(
            zb, Wot, bo, xtc, nullptr, nullptr, nullptr, nullptr, nullptr);
    }

    // ---- MLP phase (unfused; fused variants measured slower r9-r11) ----
    ln2_stats<<<T_ / 64, 256, 0, stream>>>(xt, mu2, rs2);
    for (int mc = 0; mc < 4; ++mc){
        ushort_t* xtc = xt + (size_t)mc * MCH_ * E_;
        gemm128<12, E_, HID_, 1, 1, 0><<<dim3(HID_ / 128, MCH_ / 128), 256, 0, stream>>>(
            xtc, Wm1t, bm1, hbuf, mu2 + (size_t)mc * MCH_, rs2 + (size_t)mc * MCH_,
            S1m, S2m, nullptr);
        if (bigws){
            // gemm2 writes the f32 transposed output chunk directly (MODE 4).
            ushort_t* outc = (ushort_t*)((float*)d_out + (size_t)(mc * 4) * E_ * P_);
            gemm128<48, HID_, E_, 4, 0, 0><<<dim3(E_ / 128, MCH_ / 128), 256, 0, stream>>>(
                hbuf, Wm2t, bm2, outc, nullptr, nullptr, nullptr, nullptr, xtc);
        } else {
            gemm128<48, HID_, E_, 2, 0, 0><<<dim3(E_ / 128, MCH_ / 128), 256, 0, stream>>>(
                hbuf, Wm2t, bm2, xtc, nullptr, nullptr, nullptr, nullptr, nullptr);
        }
    }

    if (!bigws)
        k4_out<<<dim3(P_ / 64, E_ / 32, B_), 256, 0, stream>>>(xt, (float*)d_out);
}

// Round 15
// 559.623 us; speedup vs baseline: 1.1900x; 1.1220x over previous
//
#include <hip/hip_runtime.h>
#include <hip/hip_bf16.h>
#include <math.h>

// ---- problem dims ----
#define B_    16
#define E_    384
#define P_    4096
#define NW_   64
#define S_    64
#define H_    12
#define DH_   32
#define HID_  1536
#define T_    65536
#define SHIFT_ 4
#define MCH_  16384   // M-chunk rows (4 batches)

typedef unsigned short ushort_t;
typedef __attribute__((ext_vector_type(8))) __bf16 b8;
typedef __attribute__((ext_vector_type(8))) ushort_t u8v;
typedef __attribute__((ext_vector_type(4))) float f4;
typedef __attribute__((ext_vector_type(4))) unsigned u32x4;

__device__ __forceinline__ float u2f(ushort_t u){
    return __uint_as_float(((unsigned)u) << 16);
}
__device__ __forceinline__ ushort_t f2u(float f){
    union { __hip_bfloat16 h; ushort_t u; } cv;
    cv.h = __float2bfloat16(f);
    return cv.u;
}
__device__ __forceinline__ unsigned pack2(float lo, float hi){
    return (unsigned)f2u(lo) | ((unsigned)f2u(hi) << 16);
}
// fast gelu: tanh-form via sigmoid, max abs err ~3e-4 (<< bf16 ulp here).
__device__ __forceinline__ float gelu_f(float v){
    const float y2 = v * (1.5957691216057308f + 0.0713548162726f * v * v);
    return v * __builtin_amdgcn_rcpf(1.f + __expf(-y2));
}

#define MFMA(a,b,c) __builtin_amdgcn_mfma_f32_16x16x32_bf16((a),(b),(c),0,0,0)

// async global->LDS, 16B per lane (lds dest must be uniform + lane*16)
#define GL2LDS(gp, lp) \
    __builtin_amdgcn_global_load_lds((const __attribute__((address_space(1))) void*)(gp), \
                                     (__attribute__((address_space(3))) void*)(lp), 16, 0, 0)

// window-order row m -> linear row p (shift+window inverse), chunk-local
template<int PERM>
__device__ __forceinline__ int rowmap(int m){
    if (PERM == 0) return m;
    const int bl = m >> 12, wn = (m >> 6) & 63, sd = m & 63;
    const int i_ = ((wn >> 3) << 3) + (sd >> 3);
    const int j_ = ((wn & 7) << 3) + (sd & 7);
    const int d1 = (i_ + SHIFT_) & 63;
    const int d2 = (j_ + SHIFT_) & 63;
    return (bl << 12) + (d1 << 6) + d2;
}

// =====================================================================
// prep_all bodies
// =====================================================================
__device__ void wt_body(int bx, int by, int tid,
    const float* __restrict__ src, ushort_t* __restrict__ dst, int K, int N,
    float scale, const float* __restrict__ gv)
{
    __shared__ float t[32][33];
    const int k0 = bx * 32, n0 = by * 32;
    const int c = tid & 31, r = tid >> 5;
    for (int rr = r; rr < 32; rr += 8)
        t[rr][c] = src[(size_t)(k0 + rr) * N + n0 + c];
    __syncthreads();
    const float gg = (gv ? gv[k0 + c] : 1.f) * scale;
    for (int rr = r; rr < 32; rr += 8)
        dst[(size_t)(n0 + rr) * K + k0 + c] = f2u(t[c][rr] * gg);
}

__device__ void lnfold_body(int bx, int tid,
    const float* __restrict__ W, const float* __restrict__ g,
    const float* __restrict__ bt, float scale, int N,
    float* __restrict__ S1, float* __restrict__ S2)
{
    __shared__ float r1[8][32], r2[8][32];
    const int c = tid & 31, ks = tid >> 5;
    const int n = bx * 32 + c;
    float s1 = 0.f, s2 = 0.f;
#pragma unroll
    for (int i = 0; i < 48; ++i){     // K = 384 = 8*48
        const int k = ks * 48 + i;
        const float w = W[(size_t)k * N + n];
        s1 += g[k] * w;
        s2 += bt[k] * w;
    }
    r1[ks][c] = s1; r2[ks][c] = s2;
    __syncthreads();
    if (tid < 32){
        float a = 0.f, b2 = 0.f;
#pragma unroll
        for (int j = 0; j < 8; ++j){ a += r1[j][tid]; b2 += r2[j][tid]; }
        S1[bx * 32 + tid] = a * scale;
        S2[bx * 32 + tid] = b2 * scale;
    }
}

// one launch for all weight transposes + LN folds + bias concat
__global__ __launch_bounds__(256) void prep_all(
    const float* Wq, const float* Wk, const float* Wv, const float* Wo,
    const float* Wm1, const float* Wm2,
    const float* ln1_g, const float* ln1_b,
    const float* ln2_g, const float* ln2_b,
    const float* bq, const float* bk, const float* bv,
    ushort_t* Wqkvt, ushort_t* Wot, ushort_t* Wm1t, ushort_t* Wm2t,
    float* S1q, float* S2q, float* S1m, float* S2m, float* bqkv)
{
    const float qscale = 0.17677669529663687f;
    const int id = blockIdx.x, tid = threadIdx.x;
    if (id < 144)       wt_body(id % 12, id / 12, tid, Wq, Wqkvt, E_, E_, qscale, ln1_g);
    else if (id < 288){ const int l = id - 144; wt_body(l % 12, l / 12, tid, Wk, Wqkvt + 384 * E_, E_, E_, 1.f, ln1_g); }
    else if (id < 432){ const int l = id - 288; wt_body(l % 12, l / 12, tid, Wv, Wqkvt + 768 * E_, E_, E_, 1.f, ln1_g); }
    else if (id < 576){ const int l = id - 432; wt_body(l % 12, l / 12, tid, Wo, Wot, E_, E_, 1.f, nullptr); }
    else if (id < 1152){ const int l = id - 576; wt_body(l % 12, l / 12, tid, Wm1, Wm1t, E_, HID_, 1.f, ln2_g); }
    else if (id < 1728){ const int l = id - 1152; wt_body(l % 48, l / 48, tid, Wm2, Wm2t, HID_, E_, 1.f, nullptr); }
    else if (id < 1740) lnfold_body(id - 1728, tid, Wq, ln1_g, ln1_b, qscale, E_, S1q, S2q);
    else if (id < 1752) lnfold_body(id - 1740, tid, Wk, ln1_g, ln1_b, 1.f, E_, S1q + 384, S2q + 384);
    else if (id < 1764) lnfold_body(id - 1752, tid, Wv, ln1_g, ln1_b, 1.f, E_, S1q + 768, S2q + 768);
    else if (id < 1812) lnfold_body(id - 1764, tid, Wm1, ln2_g, ln2_b, 1.f, HID_, S1m, S2m);
    else {
        const int i = (id - 1812) * 256 + tid;
        if (i < 1152){
            float v;
            if (i < 384)      v = bq[i] * qscale;
            else if (i < 768) v = bk[i - 384];
            else              v = bv[i - 768];
            bqkv[i] = v;
        }
    }
}

// =====================================================================
// K1: x (B,E,P) f32 -> xt bf16 (B,P,E), + LN1 stats in WINDOW order.
// 64-p-wide tiles: 256B contiguous segments, 24 indep f4 loads/thread.
// =====================================================================
__global__ __launch_bounds__(256) void k1_ln_window(
    const float* __restrict__ x, ushort_t* __restrict__ xt,
    float* __restrict__ mu1w, float* __restrict__ rs1w)
{
    __shared__ ushort_t tile[64][E_ + 2];        // bf16, stride 386
    __shared__ float redS[4][64], redQ[4][64];
    const int b = blockIdx.y, p0 = blockIdx.x * 64, tid = threadIdx.x;

    {
        const int pq = tid & 15, e00 = tid >> 4;
        const float* xp = x + ((size_t)b * E_ + e00) * P_ + p0 + pq * 4;
        f4 v[24];
#pragma unroll
        for (int i = 0; i < 24; ++i)
            v[i] = *(const f4*)(xp + (size_t)(i * 16) * P_);
        float s0 = 0.f, s1 = 0.f, s2 = 0.f, s3 = 0.f;
        float q0 = 0.f, q1 = 0.f, q2 = 0.f, q3 = 0.f;
#pragma unroll
        for (int i = 0; i < 24; ++i){
            const int e = e00 + i * 16;
            tile[pq * 4 + 0][e] = f2u(v[i][0]);
            tile[pq * 4 + 1][e] = f2u(v[i][1]);
            tile[pq * 4 + 2][e] = f2u(v[i][2]);
            tile[pq * 4 + 3][e] = f2u(v[i][3]);
            s0 += v[i][0]; q0 += v[i][0] * v[i][0];
            s1 += v[i][1]; q1 += v[i][1] * v[i][1];
            s2 += v[i][2]; q2 += v[i][2] * v[i][2];
            s3 += v[i][3]; q3 += v[i][3] * v[i][3];
        }
        s0 += __shfl_xor(s0, 16); q0 += __shfl_xor(q0, 16);
        s1 += __shfl_xor(s1, 16); q1 += __shfl_xor(q1, 16);
        s2 += __shfl_xor(s2, 16); q2 += __shfl_xor(q2, 16);
        s3 += __shfl_xor(s3, 16); q3 += __shfl_xor(q3, 16);
        s0 += __shfl_xor(s0, 32); q0 += __shfl_xor(q0, 32);
        s1 += __shfl_xor(s1, 32); q1 += __shfl_xor(q1, 32);
        s2 += __shfl_xor(s2, 32); q2 += __shfl_xor(q2, 32);
        s3 += __shfl_xor(s3, 32); q3 += __shfl_xor(q3, 32);
        const int lane = tid & 63, wvi = tid >> 6;
        if (lane < 16){
            redS[wvi][pq * 4 + 0] = s0; redQ[wvi][pq * 4 + 0] = q0;
            redS[wvi][pq * 4 + 1] = s1; redQ[wvi][pq * 4 + 1] = q1;
            redS[wvi][pq * 4 + 2] = s2; redQ[wvi][pq * 4 + 2] = q2;
            redS[wvi][pq * 4 + 3] = s3; redQ[wvi][pq * 4 + 3] = q3;
        }
    }
    __syncthreads();
    if (tid < 64){
        const float s  = redS[0][tid] + redS[1][tid] + redS[2][tid] + redS[3][tid];
        const float ss = redQ[0][tid] + redQ[1][tid] + redQ[2][tid] + redQ[3][tid];
        const float mu = s / E_;
        const float rs = rsqrtf(ss / E_ - mu * mu + 1e-5f);
        const int p = p0 + tid;
        const int d1 = p >> 6, d2 = p & 63;
        const int i_ = (d1 + 64 - SHIFT_) & 63;
        const int j_ = (d2 + 64 - SHIFT_) & 63;
        const int wsd = ((((i_ >> 3) << 3) + (j_ >> 3)) << 6)
                      + ((i_ & 7) << 3) + (j_ & 7);
        mu1w[b * P_ + wsd] = mu;
        rs1w[b * P_ + wsd] = rs;
    }

    unsigned* xtu = (unsigned*)xt;
    for (int it = 0; it < 48; ++it){
        const int idx = it * 256 + tid;
        const int pj = idx / 192, ep = idx - pj * 192;
        xtu[((size_t)b * P_ + p0 + pj) * 192 + ep] = *(const unsigned*)&tile[pj][ep * 2];
    }
}

// =====================================================================
// gemm128: C = A[M][AS] @ Bm^T + epilogue, 128x128 tiles.
// Triple-buffered LDS, counted vmcnt(4), T2 both-sides swizzle,
// T5 setprio around MFMA cluster.
// MODE 0: store bf16 nt (qkv)  1: gelu, store bf16 (h; L2-resident for
//         the immediately-following gemm2 -> NO nt)
//      2: gelu + residual RMW  3: residual RMW + window-reverse (Wo)
//      4: gelu + residual (resid ptr) -> TRANSPOSED f32 out (kills k4);
//         store quads fully contiguous per instruction (64B).
// =====================================================================
template<int KST, int AS, int OS, int MODE, int LNF, int PERM>
__global__ __launch_bounds__(256, 3) void gemm128(
    const ushort_t* __restrict__ A, const ushort_t* __restrict__ Bm,
    const float* __restrict__ bias, ushort_t* __restrict__ out,
    const float* __restrict__ mu, const float* __restrict__ rs,
    const float* __restrict__ S1, const float* __restrict__ S2,
    const ushort_t* __restrict__ resid)
{
    __shared__ __align__(16) ushort_t lds[24576];   // 3 x (A 4096 + B 4096)
    const int tid = threadIdx.x, lane = tid & 63, wv = tid >> 6;
    const int l15 = lane & 15, l4 = lane >> 4;
    const int wr = wv >> 1, wc = wv & 1;

    // XCD-aware bijective remap (all grids have nwg % 8 == 0)
    const int gx = gridDim.x;
    const int nwg = gx * gridDim.y;
    const int d = blockIdx.y * gx + blockIdx.x;
    const int cpx = nwg >> 3;
    const int lb = (d & 7) * cpx + (d >> 3);
    const int n0 = (lb % gx) * 128;
    const size_t m0 = (size_t)(lb / gx) * 128;

    // per-thread staging source offsets; quad pre-swizzled: q_g = kq^((row>>1)&3)
    const int kq = tid & 3;
    const int xq = kq ^ ((tid >> 3) & 3);
    size_t aoff0, aoff1, boff0, boff1;
    {
        const int r0 = (int)m0 + (tid >> 2);
        aoff0 = (size_t)rowmap<PERM>(r0) * AS + xq * 8;
        aoff1 = (size_t)rowmap<PERM>(r0 + 64) * AS + xq * 8;
        const int nr = n0 + (tid >> 2);
        boff0 = (size_t)nr * (KST * 32) + xq * 8;
        boff1 = boff0 + (size_t)64 * (KST * 32);
    }

#define STG(cur, k0) do { \
        ushort_t* dst_ = lds + (cur) * 8192; \
        GL2LDS(A + aoff0 + (k0), dst_ + tid * 8); \
        GL2LDS(A + aoff1 + (k0), dst_ + (256 + tid) * 8); \
        GL2LDS(Bm + boff0 + (k0), dst_ + 4096 + tid * 8); \
        GL2LDS(Bm + boff1 + (k0), dst_ + 4096 + (256 + tid) * 8); \
    } while (0)

    f4 acc[4][4];
#pragma unroll
    for (int i = 0; i < 4; ++i)
#pragma unroll
        for (int j = 0; j < 4; ++j) acc[i][j] = (f4){0.f, 0.f, 0.f, 0.f};

    const int rq = (l4 ^ ((l15 >> 1) & 3)) * 8;

    STG(0, 0);
    STG(1, 32);
    for (int ks = 0; ks < KST; ++ks){
        if (ks < KST - 1) asm volatile("s_waitcnt vmcnt(4)" ::: "memory");
        else              asm volatile("s_waitcnt vmcnt(0)" ::: "memory");
        __builtin_amdgcn_s_barrier();
        asm volatile("" ::: "memory");
        if (ks + 2 < KST) STG((ks + 2) % 3, (ks + 2) * 32);
        asm volatile("" ::: "memory");
        const ushort_t* Al = lds + (ks % 3) * 8192;
        const ushort_t* Bl = Al + 4096;
        b8 ax[4], aw[4];
#pragma unroll
        for (int f = 0; f < 4; ++f){
            ax[f] = *(const b8*)(Al + (wr * 64 + f * 16 + l15) * 32 + rq);
            aw[f] = *(const b8*)(Bl + (wc * 64 + f * 16 + l15) * 32 + rq);
        }
        __builtin_amdgcn_s_setprio(1);
#pragma unroll
        for (int fm = 0; fm < 4; ++fm)
#pragma unroll
            for (int fn = 0; fn < 4; ++fn)
                acc[fm][fn] = MFMA(aw[fn], ax[fm], acc[fm][fn]);
        __builtin_amdgcn_s_setprio(0);
    }
#undef STG

    if (MODE == 4){
        // gelu + residual (f32) -> LDS transpose [128 e][36 p] -> f32 out
        float* Tf = (float*)lds;
        float* outf = (float*)out;          // chunk base (4 batches)
#pragma unroll
        for (int rg = 0; rg < 4; ++rg){
            __syncthreads();
            if (wr == (rg >> 1)){
#pragma unroll
                for (int f2h = 0; f2h < 2; ++f2h){
                    const int fm = (rg & 1) * 2 + f2h;
                    const int m5 = f2h * 16 + l15;
                    const int grow = (int)m0 + rg * 32 + m5;
#pragma unroll
                    for (int fn = 0; fn < 4; ++fn){
                        const f4 v = acc[fm][fn];
                        const int nc = wc * 64 + fn * 16 + l4 * 4;
                        const f4 bb = *(const f4*)(bias + n0 + nc);
                        const uint2 ov = *(const uint2*)(resid + (size_t)grow * E_ + n0 + nc);
                        Tf[(nc + 0) * 36 + m5] = u2f((ushort_t)ov.x)         + gelu_f(v[0] + bb[0]);
                        Tf[(nc + 1) * 36 + m5] = u2f((ushort_t)(ov.x >> 16)) + gelu_f(v[1] + bb[1]);
                        Tf[(nc + 2) * 36 + m5] = u2f((ushort_t)ov.y)         + gelu_f(v[2] + bb[2]);
                        Tf[(nc + 3) * 36 + m5] = u2f((ushort_t)(ov.y >> 16)) + gelu_f(v[3] + bb[3]);
                    }
                }
            }
            __syncthreads();
            {
                // per instruction: lane quad covers 64B contiguous p-range
                const int growb = (int)m0 + rg * 32;
                const int bl = growb >> 12, p12 = growb & 4095;
                const int po = (tid & 3) * 4;
#pragma unroll
                for (int eh = 0; eh < 2; ++eh){
                    const int e = eh * 64 + (tid >> 2);
                    float* op = outf + ((size_t)bl * E_ + n0 + e) * P_ + p12 + po;
                    const float* tp = &Tf[e * 36 + po];
                    __builtin_nontemporal_store(*(const f4*)tp, (f4*)op);
                    __builtin_nontemporal_store(*(const f4*)(tp + 16), (f4*)(op + 16));
                }
            }
        }
        return;
    }

    // epilogue via per-wave LDS bounce [32][72] -> coalesced b128
    ushort_t* bounce = lds + wv * 2304;
    const int l8r = lane >> 3, l8c = lane & 7;
#pragma unroll
    for (int hh = 0; hh < 2; ++hh){
#pragma unroll
        for (int f2 = 0; f2 < 2; ++f2){
            const int fm = hh * 2 + f2;
            float mur = 0.f, rsr = 1.f;
            if (LNF){
                const int gm = (int)m0 + wr * 64 + fm * 16 + l15;
                mur = mu[gm]; rsr = rs[gm];
            }
#pragma unroll
            for (int fn = 0; fn < 4; ++fn){
                const f4 v = acc[fm][fn];
                const int nc = n0 + wc * 64 + fn * 16 + l4 * 4;
                const f4 bb = *(const f4*)(bias + nc);
                f4 w;
                if (LNF){
                    const f4 s1 = *(const f4*)(S1 + nc);
                    const f4 s2 = *(const f4*)(S2 + nc);
#pragma unroll
                    for (int r = 0; r < 4; ++r)
                        w[r] = rsr * v[r] - rsr * mur * s1[r] + s2[r] + bb[r];
                } else {
#pragma unroll
                    for (int r = 0; r < 4; ++r) w[r] = v[r] + bb[r];
                }
                uint2 pk;
                if (MODE == 1 || MODE == 2){
                    pk.x = pack2(gelu_f(w[0]), gelu_f(w[1]));
                    pk.y = pack2(gelu_f(w[2]), gelu_f(w[3]));
                } else {
                    pk.x = pack2(w[0], w[1]);
                    pk.y = pack2(w[2], w[3]);
                }
                *(uint2*)(bounce + (f2 * 16 + l15) * 72 + fn * 16 + l4 * 4) = pk;
            }
        }
#pragma unroll
        for (int i = 0; i < 4; ++i){
            const int br = i * 8 + l8r;
            const int grow = (int)m0 + wr * 64 + hh * 32 + br;
            const b8 yv = *(const b8*)(bounce + br * 72 + l8c * 8);
            size_t orow;
            if (MODE == 3){
                orow = (size_t)rowmap<1>(grow);
            } else {
                orow = (size_t)grow;
            }
            ushort_t* px = out + orow * OS + n0 + wc * 64 + l8c * 8;
            if (MODE >= 2){
                const b8 ov = *(const b8*)px;
                union { b8 v; unsigned u[4]; } o;
#pragma unroll
                for (int j = 0; j < 4; ++j)
                    o.u[j] = pack2((float)ov[2 * j] + (float)yv[2 * j],
                                   (float)ov[2 * j + 1] + (float)yv[2 * j + 1]);
                *(b8*)px = o.v;
            } else if (MODE == 0){
                // streaming output consumed a few launches later: nt
                union { b8 v; u32x4 q; } t; t.v = yv;
                __builtin_nontemporal_store(t.q, (u32x4*)px);
            } else {
                // MODE 1: h consumed by the NEXT launch -> keep in L2
                *(b8*)px = yv;
            }
        }
    }
}

// =====================================================================
// K2b: attention core. qkv [rows][1152] chunk-local (q|k|v, q scaled),
// block = (window, batch-in-chunk, head-group of 4). z [rows][384] out.
// =====================================================================
__global__ __launch_bounds__(256) void k2b_attn(
    const ushort_t* __restrict__ qkv,
    const float* __restrict__ pb, const float* __restrict__ mk,
    ushort_t* __restrict__ z)
{
    __shared__ __align__(16) ushort_t q_lds[64 * 32];
    __shared__ __align__(16) ushort_t k_lds[64 * 32];
    __shared__ __align__(16) ushort_t vt_lds[32 * 72];
    __shared__ __align__(16) ushort_t P_lds[64 * 72];

    const int w = blockIdx.x, bl = blockIdx.y, hz = blockIdx.z;
    const int tid = threadIdx.x, lane = tid & 63, wv = tid >> 6;
    const int l15 = lane & 15, l4 = lane >> 4;
    const int rowbase = (bl * NW_ + w) * S_;

    const int srow = tid >> 2, sqp = tid & 3;
    const int sfq = sqp ^ ((srow >> 1) & 3);
    const ushort_t* gql = qkv + (size_t)(rowbase + srow) * 1152 + sfq * 8;
    const ushort_t* gvl = qkv + (size_t)(rowbase + srow) * 1152 + 768 + sqp * 8;

    for (int hi = 0; hi < 4; ++hi){
        const int h = hz * 4 + hi;
        const int hb = h * 32;
        GL2LDS(gql + hb, q_lds + tid * 8);
        GL2LDS(gql + 384 + hb, k_lds + tid * 8);
        {
            const u8v vv = *(const u8v*)(gvl + hb);
#pragma unroll
            for (int j = 0; j < 8; ++j)
                vt_lds[(sqp * 8 + j) * 72 + srow] = vv[j];
        }
        __syncthreads();

        {
            const int qr = wv * 16 + l15;
            const int uq = qr * 4 + (l4 ^ ((qr >> 1) & 3));
            const b8 qfrag = *(const b8*)(&q_lds[uq * 8]);
            f4 sacc[4];
#pragma unroll
            for (int nt = 0; nt < 4; ++nt){
                const int kr = nt * 16 + l15;
                const int uk = kr * 4 + (l4 ^ ((kr >> 1) & 3));
                const b8 kfrag = *(const b8*)(&k_lds[uk * 8]);
                f4 c = (f4){0.f, 0.f, 0.f, 0.f};
                c = MFMA(qfrag, kfrag, c);
                const int t = nt * 16 + l15;
#pragma unroll
                for (int r = 0; r < 4; ++r){
                    const int sw = wv * 16 + l4 * 4 + r;
                    c[r] += pb[((size_t)h * S_ + sw) * S_ + t]
                          + mk[((size_t)w * S_ + sw) * S_ + t];
                }
                sacc[nt] = c;
            }
#pragma unroll
            for (int r = 0; r < 4; ++r){
                float m = fmaxf(fmaxf(sacc[0][r], sacc[1][r]),
                                fmaxf(sacc[2][r], sacc[3][r]));
                m = fmaxf(m, __shfl_xor(m, 1));
                m = fmaxf(m, __shfl_xor(m, 2));
                m = fmaxf(m, __shfl_xor(m, 4));
                m = fmaxf(m, __shfl_xor(m, 8));
                const float e0 = expf(sacc[0][r] - m), e1 = expf(sacc[1][r] - m);
                const float e2 = expf(sacc[2][r] - m), e3 = expf(sacc[3][r] - m);
                float s = e0 + e1 + e2 + e3;
                s += __shfl_xor(s, 1); s += __shfl_xor(s, 2);
                s += __shfl_xor(s, 4); s += __shfl_xor(s, 8);
                const float inv = 1.f / s;
                const int row = wv * 16 + l4 * 4 + r;
                P_lds[row * 72 +      l15] = f2u(e0 * inv);
                P_lds[row * 72 + 16 + l15] = f2u(e1 * inv);
                P_lds[row * 72 + 32 + l15] = f2u(e2 * inv);
                P_lds[row * 72 + 48 + l15] = f2u(e3 * inv);
            }
        }

        {
            f4 zacc[2];
#pragma unroll
            for (int nt = 0; nt < 2; ++nt) zacc[nt] = (f4){0.f, 0.f, 0.f, 0.f};
#pragma unroll
            for (int kb = 0; kb < 2; ++kb){
                const b8 pfrag = *(const b8*)(&P_lds[(wv * 16 + l15) * 72 + kb * 32 + l4 * 8]);
#pragma unroll
                for (int nt = 0; nt < 2; ++nt){
                    const b8 vfrag = *(const b8*)(&vt_lds[(nt * 16 + l15) * 72 + kb * 32 + l4 * 8]);
                    zacc[nt] = MFMA(pfrag, vfrag, zacc[nt]);
                }
            }
#pragma unroll
            for (int nt = 0; nt < 2; ++nt)
#pragma unroll
                for (int r = 0; r < 4; ++r){
                    const int row = wv * 16 + l4 * 4 + r;
                    z[(size_t)(rowbase + row) * E_ + hb + nt * 16 + l15] = f2u(zacc[nt][r]);
                }
        }
        __syncthreads();
    }
}

// =====================================================================
// LN2 stats only (LN2 itself folded into mlp gemm1)
// =====================================================================
__global__ __launch_bounds__(256) void ln2_stats(
    const ushort_t* __restrict__ xt, float* __restrict__ mu2, float* __restrict__ rs2)
{
    const int tid = threadIdx.x;
    const int lr = blockIdx.x * 64 + (tid >> 2), q = tid & 3;
    const ushort_t* rp = xt + (size_t)lr * E_;
    float s = 0.f, ss = 0.f;
#pragma unroll
    for (int i = 0; i < 12; ++i){
        const b8 v = *(const b8*)(rp + q * 8 + i * 32);
#pragma unroll
        for (int j = 0; j < 8; ++j){ const float f = (float)v[j]; s += f; ss += f * f; }
    }
    s += __shfl_xor(s, 1); ss += __shfl_xor(ss, 1);
    s += __shfl_xor(s, 2); ss += __shfl_xor(ss, 2);
    if (q == 0){
        const float m = s * (1.f / E_);
        mu2[lr] = m;
        rs2[lr] = rsqrtf(ss * (1.f / E_) - m * m + 1e-5f);
    }
}

// =====================================================================
// K4 (fallback when ws too small): xt bf16 -> out f32 (B,E,P)
// =====================================================================
__global__ __launch_bounds__(256) void k4_out(
    const ushort_t* __restrict__ xt, float* __restrict__ out)
{
    __shared__ float tile[32][68];
    const int b = blockIdx.z, p0 = blockIdx.x * 64, e0 = blockIdx.y * 32;
    const int tid = threadIdx.x;
    {
        const int r = tid >> 2, c = tid & 3;
        const u8v v = *(const u8v*)(xt + ((size_t)b * P_ + p0 + r) * E_ + e0 + c * 8);
#pragma unroll
        for (int j = 0; j < 8; ++j)
            tile[c * 8 + j][r] = u2f(v[j]);
    }
    __syncthreads();
    {
        const int er = tid >> 3, pc = tid & 7;
        float* op = out + ((size_t)b * E_ + e0 + er) * P_ + p0 + pc * 8;
        const f4 v0 = *(const f4*)&tile[er][pc * 8];
        const f4 v1 = *(const f4*)&tile[er][pc * 8 + 4];
        __builtin_nontemporal_store(v0, (f4*)op);
        __builtin_nontemporal_store(v1, (f4*)(op + 4));
    }
}

// =====================================================================
extern "C" void kernel_launch(void* const* d_in, const int* in_sizes, int n_in,
                              void* d_out, int out_size, void* d_ws, size_t ws_size,
                              hipStream_t stream)
{
    const float* x      = (const float*)d_in[0];
    const float* mask   = (const float*)d_in[1];
    const float* ln1_g  = (const float*)d_in[2];
    const float* ln1_b  = (const float*)d_in[3];
    const float* Wq     = (const float*)d_in[4];
    const float* bq     = (const float*)d_in[5];
    const float* Wk     = (const float*)d_in[6];
    const float* bk     = (const float*)d_in[7];
    const float* Wv     = (const float*)d_in[8];
    const float* bv     = (const float*)d_in[9];
    const float* Wo     = (const float*)d_in[10];
    const float* bo     = (const float*)d_in[11];
    const float* pos_b  = (const float*)d_in[12];
    const float* ln2_g  = (const float*)d_in[13];
    const float* ln2_b  = (const float*)d_in[14];
    const float* Wm1    = (const float*)d_in[15];
    const float* bm1    = (const float*)d_in[16];
    const float* Wm2    = (const float*)d_in[17];
    const float* bm2    = (const float*)d_in[18];

    // d_ws: xt at [0, 50.33MB). Big-ws layout adds h + Wm1t/Wm2t in d_ws
    // so the MLP can write the f32 output (which aliases d_out scratch)
    // directly from gemm2 (MODE 4) and skip k4.
    ushort_t* xt = (ushort_t*)d_ws;
    const bool bigws = ws_size >= (size_t)103022592;

    ushort_t* scratch = (ushort_t*)d_out;
    ushort_t* zb    = scratch;
    ushort_t* hbuf  = bigws ? (xt + 25165824) : scratch;   // 50.33MB region
    ushort_t* Wqkvt = scratch + 25165824;
    ushort_t* Wot   = Wqkvt + 1152 * E_;
    ushort_t* Wm1t  = bigws ? (xt + 50331648) : (Wot + E_ * E_);
    ushort_t* Wm2t  = Wm1t + E_ * HID_;
    ushort_t* qkvb  = scratch + 26935296;
    float*    bqkv  = (float*)(scratch + 45809664);   // 1152
    float*    S1q   = (float*)(scratch + 45811968);   // 1152
    float*    S2q   = (float*)(scratch + 45814272);   // 1152
    float*    S1m   = (float*)(scratch + 45816576);   // 1536
    float*    S2m   = (float*)(scratch + 45819648);   // 1536
    float*    mu1w  = (float*)(scratch + 45822720);   // 65536
    float*    rs1w  = (float*)(scratch + 45953792);   // 65536
    float*    mu2   = (float*)(scratch + 46084864);   // 65536
    float*    rs2   = (float*)(scratch + 46215936);   // 65536

    // ---- all prep in one launch ----
    prep_all<<<1817, 256, 0, stream>>>(Wq, Wk, Wv, Wo, Wm1, Wm2,
        ln1_g, ln1_b, ln2_g, ln2_b, bq, bk, bv,
        Wqkvt, Wot, Wm1t, Wm2t, S1q, S2q, S1m, S2m, bqkv);

    k1_ln_window<<<dim3(P_ / 64, B_), 256, 0, stream>>>(x, xt, mu1w, rs1w);

    // ---- attention phase: 4 chunks of 4 batches ----
    for (int mc = 0; mc < 4; ++mc){
        ushort_t* xtc = xt + (size_t)mc * MCH_ * E_;
        gemm128<12, E_, 1152, 0, 1, 1><<<dim3(9, MCH_ / 128), 256, 0, stream>>>(
            xtc, Wqkvt, bqkv, qkvb, mu1w + (size_t)mc * MCH_, rs1w + (size_t)mc * MCH_,
            S1q, S2q, nullptr);
        k2b_attn<<<dim3(NW_, 4, 3), 256, 0, stream>>>(qkvb, pos_b, mask, zb);
        gemm128<12, E_, E_, 3, 0, 0><<<dim3(3, MCH_ / 128), 256, 0, stream>>>(
            zb, Wot, bo, xtc, nullptr, nullptr, nullptr, nullptr, nullptr);
    }

    // ---- MLP phase (unfused; fused variants measured slower r9-r11) ----
    ln2_stats<<<T_ / 64, 256, 0, stream>>>(xt, mu2, rs2);
    for (int mc = 0; mc < 4; ++mc){
        ushort_t* xtc = xt + (size_t)mc * MCH_ * E_;
        gemm128<12, E_, HID_, 1, 1, 0><<<dim3(HID_ / 128, MCH_ / 128), 256, 0, stream>>>(
            xtc, Wm1t, bm1, hbuf, mu2 + (size_t)mc * MCH_, rs2 + (size_t)mc * MCH_,
            S1m, S2m, nullptr);
        if (bigws){
            // gemm2 writes the f32 transposed output chunk directly (MODE 4).
            ushort_t* outc = (ushort_t*)((float*)d_out + (size_t)(mc * 4) * E_ * P_);
            gemm128<48, HID_, E_, 4, 0, 0><<<dim3(E_ / 128, MCH_ / 128), 256, 0, stream>>>(
                hbuf, Wm2t, bm2, outc, nullptr, nullptr, nullptr, nullptr, xtc);
        } else {
            gemm128<48, HID_, E_, 2, 0, 0><<<dim3(E_ / 128, MCH_ / 128), 256, 0, stream>>>(
                hbuf, Wm2t, bm2, xtc, nullptr, nullptr, nullptr, nullptr, nullptr);
        }
    }

    if (!bigws)
        k4_out<<<dim3(P_ / 64, E_ / 32, B_), 256, 0, stream>>>(xt, (float*)d_out);
}

// Round 16
// 520.919 us; speedup vs baseline: 1.2785x; 1.0743x over previous
//
#include <hip/hip_runtime.h>
#include <hip/hip_bf16.h>
#include <math.h>

// ---- problem dims ----
#define B_    16
#define E_    384
#define P_    4096
#define NW_   64
#define S_    64
#define H_    12
#define DH_   32
#define HID_  1536
#define T_    65536
#define SHIFT_ 4

typedef unsigned short ushort_t;
typedef __attribute__((ext_vector_type(8))) __bf16 b8;
typedef __attribute__((ext_vector_type(8))) ushort_t u8v;
typedef __attribute__((ext_vector_type(4))) float f4;
typedef __attribute__((ext_vector_type(4))) unsigned u32x4;

__device__ __forceinline__ float u2f(ushort_t u){
    return __uint_as_float(((unsigned)u) << 16);
}
__device__ __forceinline__ ushort_t f2u(float f){
    union { __hip_bfloat16 h; ushort_t u; } cv;
    cv.h = __float2bfloat16(f);
    return cv.u;
}
__device__ __forceinline__ unsigned pack2(float lo, float hi){
    return (unsigned)f2u(lo) | ((unsigned)f2u(hi) << 16);
}
// fast gelu: tanh-form via sigmoid, max abs err ~3e-4 (<< bf16 ulp here).
__device__ __forceinline__ float gelu_f(float v){
    const float y2 = v * (1.5957691216057308f + 0.0713548162726f * v * v);
    return v * __builtin_amdgcn_rcpf(1.f + __expf(-y2));
}

#define MFMA(a,b,c) __builtin_amdgcn_mfma_f32_16x16x32_bf16((a),(b),(c),0,0,0)

// async global->LDS, 16B per lane (lds dest must be uniform + lane*16)
#define GL2LDS(gp, lp) \
    __builtin_amdgcn_global_load_lds((const __attribute__((address_space(1))) void*)(gp), \
                                     (__attribute__((address_space(3))) void*)(lp), 16, 0, 0)

// window-order row m -> linear row p (shift+window inverse), chunk-local
template<int PERM>
__device__ __forceinline__ int rowmap(int m){
    if (PERM == 0) return m;
    const int bl = m >> 12, wn = (m >> 6) & 63, sd = m & 63;
    const int i_ = ((wn >> 3) << 3) + (sd >> 3);
    const int j_ = ((wn & 7) << 3) + (sd & 7);
    const int d1 = (i_ + SHIFT_) & 63;
    const int d2 = (j_ + SHIFT_) & 63;
    return (bl << 12) + (d1 << 6) + d2;
}

// =====================================================================
// prep_all bodies
// =====================================================================
__device__ void wt_body(int bx, int by, int tid,
    const float* __restrict__ src, ushort_t* __restrict__ dst, int K, int N,
    float scale, const float* __restrict__ gv)
{
    __shared__ float t[32][33];
    const int k0 = bx * 32, n0 = by * 32;
    const int c = tid & 31, r = tid >> 5;
    for (int rr = r; rr < 32; rr += 8)
        t[rr][c] = src[(size_t)(k0 + rr) * N + n0 + c];
    __syncthreads();
    const float gg = (gv ? gv[k0 + c] : 1.f) * scale;
    for (int rr = r; rr < 32; rr += 8)
        dst[(size_t)(n0 + rr) * K + k0 + c] = f2u(t[c][rr] * gg);
}

__device__ void lnfold_body(int bx, int tid,
    const float* __restrict__ W, const float* __restrict__ g,
    const float* __restrict__ bt, float scale, int N,
    float* __restrict__ S1, float* __restrict__ S2)
{
    __shared__ float r1[8][32], r2[8][32];
    const int c = tid & 31, ks = tid >> 5;
    const int n = bx * 32 + c;
    float s1 = 0.f, s2 = 0.f;
#pragma unroll
    for (int i = 0; i < 48; ++i){     // K = 384 = 8*48
        const int k = ks * 48 + i;
        const float w = W[(size_t)k * N + n];
        s1 += g[k] * w;
        s2 += bt[k] * w;
    }
    r1[ks][c] = s1; r2[ks][c] = s2;
    __syncthreads();
    if (tid < 32){
        float a = 0.f, b2 = 0.f;
#pragma unroll
        for (int j = 0; j < 8; ++j){ a += r1[j][tid]; b2 += r2[j][tid]; }
        S1[bx * 32 + tid] = a * scale;
        S2[bx * 32 + tid] = b2 * scale;
    }
}

// one launch for all weight transposes + LN folds + bias concat
__global__ __launch_bounds__(256) void prep_all(
    const float* Wq, const float* Wk, const float* Wv, const float* Wo,
    const float* Wm1, const float* Wm2,
    const float* ln1_g, const float* ln1_b,
    const float* ln2_g, const float* ln2_b,
    const float* bq, const float* bk, const float* bv,
    ushort_t* Wqkvt, ushort_t* Wot, ushort_t* Wm1t, ushort_t* Wm2t,
    float* S1q, float* S2q, float* S1m, float* S2m, float* bqkv)
{
    const float qscale = 0.17677669529663687f;
    const int id = blockIdx.x, tid = threadIdx.x;
    if (id < 144)       wt_body(id % 12, id / 12, tid, Wq, Wqkvt, E_, E_, qscale, ln1_g);
    else if (id < 288){ const int l = id - 144; wt_body(l % 12, l / 12, tid, Wk, Wqkvt + 384 * E_, E_, E_, 1.f, ln1_g); }
    else if (id < 432){ const int l = id - 288; wt_body(l % 12, l / 12, tid, Wv, Wqkvt + 768 * E_, E_, E_, 1.f, ln1_g); }
    else if (id < 576){ const int l = id - 432; wt_body(l % 12, l / 12, tid, Wo, Wot, E_, E_, 1.f, nullptr); }
    else if (id < 1152){ const int l = id - 576; wt_body(l % 12, l / 12, tid, Wm1, Wm1t, E_, HID_, 1.f, ln2_g); }
    else if (id < 1728){ const int l = id - 1152; wt_body(l % 48, l / 48, tid, Wm2, Wm2t, HID_, E_, 1.f, nullptr); }
    else if (id < 1740) lnfold_body(id - 1728, tid, Wq, ln1_g, ln1_b, qscale, E_, S1q, S2q);
    else if (id < 1752) lnfold_body(id - 1740, tid, Wk, ln1_g, ln1_b, 1.f, E_, S1q + 384, S2q + 384);
    else if (id < 1764) lnfold_body(id - 1752, tid, Wv, ln1_g, ln1_b, 1.f, E_, S1q + 768, S2q + 768);
    else if (id < 1812) lnfold_body(id - 1764, tid, Wm1, ln2_g, ln2_b, 1.f, HID_, S1m, S2m);
    else {
        const int i = (id - 1812) * 256 + tid;
        if (i < 1152){
            float v;
            if (i < 384)      v = bq[i] * qscale;
            else if (i < 768) v = bk[i - 384];
            else              v = bv[i - 768];
            bqkv[i] = v;
        }
    }
}

// =====================================================================
// K1: x (B,E,P) f32 -> xt bf16 (B,P,E), + LN1 stats in WINDOW order.
// =====================================================================
__global__ __launch_bounds__(256) void k1_ln_window(
    const float* __restrict__ x, ushort_t* __restrict__ xt,
    float* __restrict__ mu1w, float* __restrict__ rs1w)
{
    __shared__ ushort_t tile[64][E_ + 2];        // bf16, stride 386
    __shared__ float redS[4][64], redQ[4][64];
    const int b = blockIdx.y, p0 = blockIdx.x * 64, tid = threadIdx.x;

    {
        const int pq = tid & 15, e00 = tid >> 4;
        const float* xp = x + ((size_t)b * E_ + e00) * P_ + p0 + pq * 4;
        f4 v[24];
#pragma unroll
        for (int i = 0; i < 24; ++i)
            v[i] = *(const f4*)(xp + (size_t)(i * 16) * P_);
        float s0 = 0.f, s1 = 0.f, s2 = 0.f, s3 = 0.f;
        float q0 = 0.f, q1 = 0.f, q2 = 0.f, q3 = 0.f;
#pragma unroll
        for (int i = 0; i < 24; ++i){
            const int e = e00 + i * 16;
            tile[pq * 4 + 0][e] = f2u(v[i][0]);
            tile[pq * 4 + 1][e] = f2u(v[i][1]);
            tile[pq * 4 + 2][e] = f2u(v[i][2]);
            tile[pq * 4 + 3][e] = f2u(v[i][3]);
            s0 += v[i][0]; q0 += v[i][0] * v[i][0];
            s1 += v[i][1]; q1 += v[i][1] * v[i][1];
            s2 += v[i][2]; q2 += v[i][2] * v[i][2];
            s3 += v[i][3]; q3 += v[i][3] * v[i][3];
        }
        s0 += __shfl_xor(s0, 16); q0 += __shfl_xor(q0, 16);
        s1 += __shfl_xor(s1, 16); q1 += __shfl_xor(q1, 16);
        s2 += __shfl_xor(s2, 16); q2 += __shfl_xor(q2, 16);
        s3 += __shfl_xor(s3, 16); q3 += __shfl_xor(q3, 16);
        s0 += __shfl_xor(s0, 32); q0 += __shfl_xor(q0, 32);
        s1 += __shfl_xor(s1, 32); q1 += __shfl_xor(q1, 32);
        s2 += __shfl_xor(s2, 32); q2 += __shfl_xor(q2, 32);
        s3 += __shfl_xor(s3, 32); q3 += __shfl_xor(q3, 32);
        const int lane = tid & 63, wvi = tid >> 6;
        if (lane < 16){
            redS[wvi][pq * 4 + 0] = s0; redQ[wvi][pq * 4 + 0] = q0;
            redS[wvi][pq * 4 + 1] = s1; redQ[wvi][pq * 4 + 1] = q1;
            redS[wvi][pq * 4 + 2] = s2; redQ[wvi][pq * 4 + 2] = q2;
            redS[wvi][pq * 4 + 3] = s3; redQ[wvi][pq * 4 + 3] = q3;
        }
    }
    __syncthreads();
    if (tid < 64){
        const float s  = redS[0][tid] + redS[1][tid] + redS[2][tid] + redS[3][tid];
        const float ss = redQ[0][tid] + redQ[1][tid] + redQ[2][tid] + redQ[3][tid];
        const float mu = s / E_;
        const float rs = rsqrtf(ss / E_ - mu * mu + 1e-5f);
        const int p = p0 + tid;
        const int d1 = p >> 6, d2 = p & 63;
        const int i_ = (d1 + 64 - SHIFT_) & 63;
        const int j_ = (d2 + 64 - SHIFT_) & 63;
        const int wsd = ((((i_ >> 3) << 3) + (j_ >> 3)) << 6)
                      + ((i_ & 7) << 3) + (j_ & 7);
        mu1w[b * P_ + wsd] = mu;
        rs1w[b * P_ + wsd] = rs;
    }

    unsigned* xtu = (unsigned*)xt;
    for (int it = 0; it < 48; ++it){
        const int idx = it * 256 + tid;
        const int pj = idx / 192, ep = idx - pj * 192;
        xtu[((size_t)b * P_ + p0 + pj) * 192 + ep] = *(const unsigned*)&tile[pj][ep * 2];
    }
}

// =====================================================================
// gemm128: C = A[M][AS] @ Bm^T + epilogue, 128x128 tiles.
// Triple-buffered LDS, counted vmcnt(4), T2 both-sides swizzle,
// T5 setprio around MFMA cluster.
// MODE 0: store bf16 nt (qkv)  1: gelu, store bf16 (h; L2/L3-resident)
//      2: gelu + residual RMW  3: residual RMW + window-reverse (Wo)
//      4: gelu + residual (resid ptr) -> TRANSPOSED f32 out (kills k4)
// =====================================================================
template<int KST, int AS, int OS, int MODE, int LNF, int PERM>
__global__ __launch_bounds__(256, 3) void gemm128(
    const ushort_t* __restrict__ A, const ushort_t* __restrict__ Bm,
    const float* __restrict__ bias, ushort_t* __restrict__ out,
    const float* __restrict__ mu, const float* __restrict__ rs,
    const float* __restrict__ S1, const float* __restrict__ S2,
    const ushort_t* __restrict__ resid)
{
    __shared__ __align__(16) ushort_t lds[24576];   // 3 x (A 4096 + B 4096)
    const int tid = threadIdx.x, lane = tid & 63, wv = tid >> 6;
    const int l15 = lane & 15, l4 = lane >> 4;
    const int wr = wv >> 1, wc = wv & 1;

    // XCD-aware bijective remap (all grids have nwg % 8 == 0)
    const int gx = gridDim.x;
    const int nwg = gx * gridDim.y;
    const int d = blockIdx.y * gx + blockIdx.x;
    const int cpx = nwg >> 3;
    const int lb = (d & 7) * cpx + (d >> 3);
    const int n0 = (lb % gx) * 128;
    const size_t m0 = (size_t)(lb / gx) * 128;

    // per-thread staging source offsets; quad pre-swizzled: q_g = kq^((row>>1)&3)
    const int kq = tid & 3;
    const int xq = kq ^ ((tid >> 3) & 3);
    size_t aoff0, aoff1, boff0, boff1;
    {
        const int r0 = (int)m0 + (tid >> 2);
        aoff0 = (size_t)rowmap<PERM>(r0) * AS + xq * 8;
        aoff1 = (size_t)rowmap<PERM>(r0 + 64) * AS + xq * 8;
        const int nr = n0 + (tid >> 2);
        boff0 = (size_t)nr * (KST * 32) + xq * 8;
        boff1 = boff0 + (size_t)64 * (KST * 32);
    }

#define STG(cur, k0) do { \
        ushort_t* dst_ = lds + (cur) * 8192; \
        GL2LDS(A + aoff0 + (k0), dst_ + tid * 8); \
        GL2LDS(A + aoff1 + (k0), dst_ + (256 + tid) * 8); \
        GL2LDS(Bm + boff0 + (k0), dst_ + 4096 + tid * 8); \
        GL2LDS(Bm + boff1 + (k0), dst_ + 4096 + (256 + tid) * 8); \
    } while (0)

    f4 acc[4][4];
#pragma unroll
    for (int i = 0; i < 4; ++i)
#pragma unroll
        for (int j = 0; j < 4; ++j) acc[i][j] = (f4){0.f, 0.f, 0.f, 0.f};

    const int rq = (l4 ^ ((l15 >> 1) & 3)) * 8;

    STG(0, 0);
    STG(1, 32);
    for (int ks = 0; ks < KST; ++ks){
        if (ks < KST - 1) asm volatile("s_waitcnt vmcnt(4)" ::: "memory");
        else              asm volatile("s_waitcnt vmcnt(0)" ::: "memory");
        __builtin_amdgcn_s_barrier();
        asm volatile("" ::: "memory");
        if (ks + 2 < KST) STG((ks + 2) % 3, (ks + 2) * 32);
        asm volatile("" ::: "memory");
        const ushort_t* Al = lds + (ks % 3) * 8192;
        const ushort_t* Bl = Al + 4096;
        b8 ax[4], aw[4];
#pragma unroll
        for (int f = 0; f < 4; ++f){
            ax[f] = *(const b8*)(Al + (wr * 64 + f * 16 + l15) * 32 + rq);
            aw[f] = *(const b8*)(Bl + (wc * 64 + f * 16 + l15) * 32 + rq);
        }
        __builtin_amdgcn_s_setprio(1);
#pragma unroll
        for (int fm = 0; fm < 4; ++fm)
#pragma unroll
            for (int fn = 0; fn < 4; ++fn)
                acc[fm][fn] = MFMA(aw[fn], ax[fm], acc[fm][fn]);
        __builtin_amdgcn_s_setprio(0);
    }
#undef STG

    if (MODE == 4){
        // gelu + residual (f32) -> LDS transpose [128 e][36 p] -> f32 out
        float* Tf = (float*)lds;
        float* outf = (float*)out;          // chunk base
#pragma unroll
        for (int rg = 0; rg < 4; ++rg){
            __syncthreads();
            if (wr == (rg >> 1)){
#pragma unroll
                for (int f2h = 0; f2h < 2; ++f2h){
                    const int fm = (rg & 1) * 2 + f2h;
                    const int m5 = f2h * 16 + l15;
                    const int grow = (int)m0 + rg * 32 + m5;
#pragma unroll
                    for (int fn = 0; fn < 4; ++fn){
                        const f4 v = acc[fm][fn];
                        const int nc = wc * 64 + fn * 16 + l4 * 4;
                        const f4 bb = *(const f4*)(bias + n0 + nc);
                        const uint2 ov = *(const uint2*)(resid + (size_t)grow * E_ + n0 + nc);
                        Tf[(nc + 0) * 36 + m5] = u2f((ushort_t)ov.x)         + gelu_f(v[0] + bb[0]);
                        Tf[(nc + 1) * 36 + m5] = u2f((ushort_t)(ov.x >> 16)) + gelu_f(v[1] + bb[1]);
                        Tf[(nc + 2) * 36 + m5] = u2f((ushort_t)ov.y)         + gelu_f(v[2] + bb[2]);
                        Tf[(nc + 3) * 36 + m5] = u2f((ushort_t)(ov.y >> 16)) + gelu_f(v[3] + bb[3]);
                    }
                }
            }
            __syncthreads();
            {
                // per instruction: lane quad covers 64B contiguous p-range
                const int growb = (int)m0 + rg * 32;
                const int bl = growb >> 12, p12 = growb & 4095;
                const int po = (tid & 3) * 4;
#pragma unroll
                for (int eh = 0; eh < 2; ++eh){
                    const int e = eh * 64 + (tid >> 2);
                    float* op = outf + ((size_t)bl * E_ + n0 + e) * P_ + p12 + po;
                    const float* tp = &Tf[e * 36 + po];
                    __builtin_nontemporal_store(*(const f4*)tp, (f4*)op);
                    __builtin_nontemporal_store(*(const f4*)(tp + 16), (f4*)(op + 16));
                }
            }
        }
        return;
    }

    // epilogue via per-wave LDS bounce [32][72] -> coalesced b128
    ushort_t* bounce = lds + wv * 2304;
    const int l8r = lane >> 3, l8c = lane & 7;
#pragma unroll
    for (int hh = 0; hh < 2; ++hh){
#pragma unroll
        for (int f2 = 0; f2 < 2; ++f2){
            const int fm = hh * 2 + f2;
            float mur = 0.f, rsr = 1.f;
            if (LNF){
                const int gm = (int)m0 + wr * 64 + fm * 16 + l15;
                mur = mu[gm]; rsr = rs[gm];
            }
#pragma unroll
            for (int fn = 0; fn < 4; ++fn){
                const f4 v = acc[fm][fn];
                const int nc = n0 + wc * 64 + fn * 16 + l4 * 4;
                const f4 bb = *(const f4*)(bias + nc);
                f4 w;
                if (LNF){
                    const f4 s1 = *(const f4*)(S1 + nc);
                    const f4 s2 = *(const f4*)(S2 + nc);
#pragma unroll
                    for (int r = 0; r < 4; ++r)
                        w[r] = rsr * v[r] - rsr * mur * s1[r] + s2[r] + bb[r];
                } else {
#pragma unroll
                    for (int r = 0; r < 4; ++r) w[r] = v[r] + bb[r];
                }
                uint2 pk;
                if (MODE == 1 || MODE == 2){
                    pk.x = pack2(gelu_f(w[0]), gelu_f(w[1]));
                    pk.y = pack2(gelu_f(w[2]), gelu_f(w[3]));
                } else {
                    pk.x = pack2(w[0], w[1]);
                    pk.y = pack2(w[2], w[3]);
                }
                *(uint2*)(bounce + (f2 * 16 + l15) * 72 + fn * 16 + l4 * 4) = pk;
            }
        }
#pragma unroll
        for (int i = 0; i < 4; ++i){
            const int br = i * 8 + l8r;
            const int grow = (int)m0 + wr * 64 + hh * 32 + br;
            const b8 yv = *(const b8*)(bounce + br * 72 + l8c * 8);
            size_t orow;
            if (MODE == 3){
                orow = (size_t)rowmap<1>(grow);
            } else {
                orow = (size_t)grow;
            }
            ushort_t* px = out + orow * OS + n0 + wc * 64 + l8c * 8;
            if (MODE >= 2){
                const b8 ov = *(const b8*)px;
                union { b8 v; unsigned u[4]; } o;
#pragma unroll
                for (int j = 0; j < 4; ++j)
                    o.u[j] = pack2((float)ov[2 * j] + (float)yv[2 * j],
                                   (float)ov[2 * j + 1] + (float)yv[2 * j + 1]);
                *(b8*)px = o.v;
            } else if (MODE == 0){
                union { b8 v; u32x4 q; } t; t.v = yv;
                __builtin_nontemporal_store(t.q, (u32x4*)px);
            } else {
                // MODE 1: h consumed by the NEXT launch -> keep in L2
                *(b8*)px = yv;
            }
        }
    }
}

// =====================================================================
// K2b: attention core. qkv [rows][1152] chunk-local (q|k|v, q scaled),
// block = (window, batch-in-chunk, head-group of 4). z [rows][384] out.
// =====================================================================
__global__ __launch_bounds__(256) void k2b_attn(
    const ushort_t* __restrict__ qkv,
    const float* __restrict__ pb, const float* __restrict__ mk,
    ushort_t* __restrict__ z)
{
    __shared__ __align__(16) ushort_t q_lds[64 * 32];
    __shared__ __align__(16) ushort_t k_lds[64 * 32];
    __shared__ __align__(16) ushort_t vt_lds[32 * 72];
    __shared__ __align__(16) ushort_t P_lds[64 * 72];

    const int w = blockIdx.x, bl = blockIdx.y, hz = blockIdx.z;
    const int tid = threadIdx.x, lane = tid & 63, wv = tid >> 6;
    const int l15 = lane & 15, l4 = lane >> 4;
    const int rowbase = (bl * NW_ + w) * S_;

    const int srow = tid >> 2, sqp = tid & 3;
    const int sfq = sqp ^ ((srow >> 1) & 3);
    const ushort_t* gql = qkv + (size_t)(rowbase + srow) * 1152 + sfq * 8;
    const ushort_t* gvl = qkv + (size_t)(rowbase + srow) * 1152 + 768 + sqp * 8;

    for (int hi = 0; hi < 4; ++hi){
        const int h = hz * 4 + hi;
        const int hb = h * 32;
        GL2LDS(gql + hb, q_lds + tid * 8);
        GL2LDS(gql + 384 + hb, k_lds + tid * 8);
        {
            const u8v vv = *(const u8v*)(gvl + hb);
#pragma unroll
            for (int j = 0; j < 8; ++j)
                vt_lds[(sqp * 8 + j) * 72 + srow] = vv[j];
        }
        __syncthreads();

        {
            const int qr = wv * 16 + l15;
            const int uq = qr * 4 + (l4 ^ ((qr >> 1) & 3));
            const b8 qfrag = *(const b8*)(&q_lds[uq * 8]);
            f4 sacc[4];
#pragma unroll
            for (int nt = 0; nt < 4; ++nt){
                const int kr = nt * 16 + l15;
                const int uk = kr * 4 + (l4 ^ ((kr >> 1) & 3));
                const b8 kfrag = *(const b8*)(&k_lds[uk * 8]);
                f4 c = (f4){0.f, 0.f, 0.f, 0.f};
                c = MFMA(qfrag, kfrag, c);
                const int t = nt * 16 + l15;
#pragma unroll
                for (int r = 0; r < 4; ++r){
                    const int sw = wv * 16 + l4 * 4 + r;
                    c[r] += pb[((size_t)h * S_ + sw) * S_ + t]
                          + mk[((size_t)w * S_ + sw) * S_ + t];
                }
                sacc[nt] = c;
            }
#pragma unroll
            for (int r = 0; r < 4; ++r){
                float m = fmaxf(fmaxf(sacc[0][r], sacc[1][r]),
                                fmaxf(sacc[2][r], sacc[3][r]));
                m = fmaxf(m, __shfl_xor(m, 1));
                m = fmaxf(m, __shfl_xor(m, 2));
                m = fmaxf(m, __shfl_xor(m, 4));
                m = fmaxf(m, __shfl_xor(m, 8));
                const float e0 = expf(sacc[0][r] - m), e1 = expf(sacc[1][r] - m);
                const float e2 = expf(sacc[2][r] - m), e3 = expf(sacc[3][r] - m);
                float s = e0 + e1 + e2 + e3;
                s += __shfl_xor(s, 1); s += __shfl_xor(s, 2);
                s += __shfl_xor(s, 4); s += __shfl_xor(s, 8);
                const float inv = 1.f / s;
                const int row = wv * 16 + l4 * 4 + r;
                P_lds[row * 72 +      l15] = f2u(e0 * inv);
                P_lds[row * 72 + 16 + l15] = f2u(e1 * inv);
                P_lds[row * 72 + 32 + l15] = f2u(e2 * inv);
                P_lds[row * 72 + 48 + l15] = f2u(e3 * inv);
            }
        }

        {
            f4 zacc[2];
#pragma unroll
            for (int nt = 0; nt < 2; ++nt) zacc[nt] = (f4){0.f, 0.f, 0.f, 0.f};
#pragma unroll
            for (int kb = 0; kb < 2; ++kb){
                const b8 pfrag = *(const b8*)(&P_lds[(wv * 16 + l15) * 72 + kb * 32 + l4 * 8]);
#pragma unroll
                for (int nt = 0; nt < 2; ++nt){
                    const b8 vfrag = *(const b8*)(&vt_lds[(nt * 16 + l15) * 72 + kb * 32 + l4 * 8]);
                    zacc[nt] = MFMA(pfrag, vfrag, zacc[nt]);
                }
            }
#pragma unroll
            for (int nt = 0; nt < 2; ++nt)
#pragma unroll
                for (int r = 0; r < 4; ++r){
                    const int row = wv * 16 + l4 * 4 + r;
                    z[(size_t)(rowbase + row) * E_ + hb + nt * 16 + l15] = f2u(zacc[nt][r]);
                }
        }
        __syncthreads();
    }
}

// =====================================================================
// LN2 stats only (LN2 itself folded into mlp gemm1)
// =====================================================================
__global__ __launch_bounds__(256) void ln2_stats(
    const ushort_t* __restrict__ xt, float* __restrict__ mu2, float* __restrict__ rs2)
{
    const int tid = threadIdx.x;
    const int lr = blockIdx.x * 64 + (tid >> 2), q = tid & 3;
    const ushort_t* rp = xt + (size_t)lr * E_;
    float s = 0.f, ss = 0.f;
#pragma unroll
    for (int i = 0; i < 12; ++i){
        const b8 v = *(const b8*)(rp + q * 8 + i * 32);
#pragma unroll
        for (int j = 0; j < 8; ++j){ const float f = (float)v[j]; s += f; ss += f * f; }
    }
    s += __shfl_xor(s, 1); ss += __shfl_xor(ss, 1);
    s += __shfl_xor(s, 2); ss += __shfl_xor(ss, 2);
    if (q == 0){
        const float m = s * (1.f / E_);
        mu2[lr] = m;
        rs2[lr] = rsqrtf(ss * (1.f / E_) - m * m + 1e-5f);
    }
}

// =====================================================================
// K4 (fallback when ws too small): xt bf16 -> out f32 (B,E,P)
// =====================================================================
__global__ __launch_bounds__(256) void k4_out(
    const ushort_t* __restrict__ xt, float* __restrict__ out)
{
    __shared__ float tile[32][68];
    const int b = blockIdx.z, p0 = blockIdx.x * 64, e0 = blockIdx.y * 32;
    const int tid = threadIdx.x;
    {
        const int r = tid >> 2, c = tid & 3;
        const u8v v = *(const u8v*)(xt + ((size_t)b * P_ + p0 + r) * E_ + e0 + c * 8);
#pragma unroll
        for (int j = 0; j < 8; ++j)
            tile[c * 8 + j][r] = u2f(v[j]);
    }
    __syncthreads();
    {
        const int er = tid >> 3, pc = tid & 7;
        float* op = out + ((size_t)b * E_ + e0 + er) * P_ + p0 + pc * 8;
        const f4 v0 = *(const f4*)&tile[er][pc * 8];
        const f4 v1 = *(const f4*)&tile[er][pc * 8 + 4];
        __builtin_nontemporal_store(v0, (f4*)op);
        __builtin_nontemporal_store(v1, (f4*)(op + 4));
    }
}

// =====================================================================
extern "C" void kernel_launch(void* const* d_in, const int* in_sizes, int n_in,
                              void* d_out, int out_size, void* d_ws, size_t ws_size,
                              hipStream_t stream)
{
    const float* x      = (const float*)d_in[0];
    const float* mask   = (const float*)d_in[1];
    const float* ln1_g  = (const float*)d_in[2];
    const float* ln1_b  = (const float*)d_in[3];
    const float* Wq     = (const float*)d_in[4];
    const float* bq     = (const float*)d_in[5];
    const float* Wk     = (const float*)d_in[6];
    const float* bk     = (const float*)d_in[7];
    const float* Wv     = (const float*)d_in[8];
    const float* bv     = (const float*)d_in[9];
    const float* Wo     = (const float*)d_in[10];
    const float* bo     = (const float*)d_in[11];
    const float* pos_b  = (const float*)d_in[12];
    const float* ln2_g  = (const float*)d_in[13];
    const float* ln2_b  = (const float*)d_in[14];
    const float* Wm1    = (const float*)d_in[15];
    const float* bm1    = (const float*)d_in[16];
    const float* Wm2    = (const float*)d_in[17];
    const float* bm2    = (const float*)d_in[18];

    ushort_t* xt = (ushort_t*)d_ws;
    const bool bigws = ws_size >= (size_t)103022592;
    ushort_t* scratch = (ushort_t*)d_out;

    if (bigws){
        // ---- bigws layout ----
        // scratch: [0, 37748736)  qkvb (2-chunk attention: 32768 rows x 1152)
        //          [37748736, +442368)  Wqkvt ; then Wot (+147456); then consts.
        //   MODE4 out-writes: chunk mc covers ushorts [mc*12582912, +12582912);
        //   chunks 0-2 clobber qkvb (dead), chunk 3 clobbers weights+consts --
        //   all their readers complete earlier in stream order (audited r15).
        // ws: xt [0, 50.33MB) | zb/hbuf region [50.33MB, 100.66MB) | Wm1t/Wm2t.
        ushort_t* qkvb  = scratch;
        ushort_t* Wqkvt = scratch + 37748736;
        ushort_t* Wot   = Wqkvt + 1152 * E_;
        float*    bqkv  = (float*)(scratch + 38338560);
        float*    S1q   = (float*)(scratch + 38340864);
        float*    S2q   = (float*)(scratch + 38343168);
        float*    S1m   = (float*)(scratch + 38345472);
        float*    S2m   = (float*)(scratch + 38348544);
        float*    mu1w  = (float*)(scratch + 38351616);   // 65536 f32
        float*    rs1w  = (float*)(scratch + 38482688);
        float*    mu2   = (float*)(scratch + 38613760);
        float*    rs2   = (float*)(scratch + 38744832);   // ends 38875904
        ushort_t* zb    = xt + 25165824;                  // 12.58M used of 25.17M
        ushort_t* hbuf  = xt + 25165824;                  // MLP phase reuse
        ushort_t* Wm1t  = xt + 50331648;
        ushort_t* Wm2t  = Wm1t + E_ * HID_;

        prep_all<<<1817, 256, 0, stream>>>(Wq, Wk, Wv, Wo, Wm1, Wm2,
            ln1_g, ln1_b, ln2_g, ln2_b, bq, bk, bv,
            Wqkvt, Wot, Wm1t, Wm2t, S1q, S2q, S1m, S2m, bqkv);

        k1_ln_window<<<dim3(P_ / 64, B_), 256, 0, stream>>>(x, xt, mu1w, rs1w);

        // ---- attention phase: 2 chunks of 8 batches (32768 rows) ----
        for (int mc = 0; mc < 2; ++mc){
            ushort_t* xtc = xt + (size_t)mc * 32768 * E_;
            gemm128<12, E_, 1152, 0, 1, 1><<<dim3(9, 256), 256, 0, stream>>>(
                xtc, Wqkvt, bqkv, qkvb, mu1w + (size_t)mc * 32768,
                rs1w + (size_t)mc * 32768, S1q, S2q, nullptr);
            k2b_attn<<<dim3(NW_, 8, 3), 256, 0, stream>>>(qkvb, pos_b, mask, zb);
            gemm128<12, E_, E_, 3, 0, 0><<<dim3(3, 256), 256, 0, stream>>>(
                zb, Wot, bo, xtc, nullptr, nullptr, nullptr, nullptr, nullptr);
        }

        // ---- MLP phase: 4 chunks of 16384 rows (hbuf capacity bound) ----
        ln2_stats<<<T_ / 64, 256, 0, stream>>>(xt, mu2, rs2);
        for (int mc = 0; mc < 4; ++mc){
            ushort_t* xtc = xt + (size_t)mc * 16384 * E_;
            gemm128<12, E_, HID_, 1, 1, 0><<<dim3(HID_ / 128, 128), 256, 0, stream>>>(
                xtc, Wm1t, bm1, hbuf, mu2 + (size_t)mc * 16384,
                rs2 + (size_t)mc * 16384, S1m, S2m, nullptr);
            ushort_t* outc = (ushort_t*)((float*)d_out + (size_t)(mc * 4) * E_ * P_);
            gemm128<48, HID_, E_, 4, 0, 0><<<dim3(E_ / 128, 128), 256, 0, stream>>>(
                hbuf, Wm2t, bm2, outc, nullptr, nullptr, nullptr, nullptr, xtc);
        }
    } else {
        // ---- fallback (r15 path): 4-chunk attention, MODE2 + k4 ----
        ushort_t* zb    = scratch;
        ushort_t* hbuf  = scratch;
        ushort_t* Wqkvt = scratch + 25165824;
        ushort_t* Wot   = Wqkvt + 1152 * E_;
        ushort_t* Wm1t  = Wot + E_ * E_;
        ushort_t* Wm2t  = Wm1t + E_ * HID_;
        ushort_t* qkvb  = scratch + 26935296;
        float*    bqkv  = (float*)(scratch + 45809664);
        float*    S1q   = (float*)(scratch + 45811968);
        float*    S2q   = (float*)(scratch + 45814272);
        float*    S1m   = (float*)(scratch + 45816576);
        float*    S2m   = (float*)(scratch + 45819648);
        float*    mu1w  = (float*)(scratch + 45822720);
        float*    rs1w  = (float*)(scratch + 45953792);
        float*    mu2   = (float*)(scratch + 46084864);
        float*    rs2   = (float*)(scratch + 46215936);

        prep_all<<<1817, 256, 0, stream>>>(Wq, Wk, Wv, Wo, Wm1, Wm2,
            ln1_g, ln1_b, ln2_g, ln2_b, bq, bk, bv,
            Wqkvt, Wot, Wm1t, Wm2t, S1q, S2q, S1m, S2m, bqkv);

        k1_ln_window<<<dim3(P_ / 64, B_), 256, 0, stream>>>(x, xt, mu1w, rs1w);

        for (int mc = 0; mc < 4; ++mc){
            ushort_t* xtc = xt + (size_t)mc * 16384 * E_;
            gemm128<12, E_, 1152, 0, 1, 1><<<dim3(9, 128), 256, 0, stream>>>(
                xtc, Wqkvt, bqkv, qkvb, mu1w + (size_t)mc * 16384,
                rs1w + (size_t)mc * 16384, S1q, S2q, nullptr);
            k2b_attn<<<dim3(NW_, 4, 3), 256, 0, stream>>>(qkvb, pos_b, mask, zb);
            gemm128<12, E_, E_, 3, 0, 0><<<dim3(3, 128), 256, 0, stream>>>(
                zb, Wot, bo, xtc, nullptr, nullptr, nullptr, nullptr, nullptr);
        }

        ln2_stats<<<T_ / 64, 256, 0, stream>>>(xt, mu2, rs2);
        for (int mc = 0; mc < 4; ++mc){
            ushort_t* xtc = xt + (size_t)mc * 16384 * E_;
            gemm128<12, E_, HID_, 1, 1, 0><<<dim3(HID_ / 128, 128), 256, 0, stream>>>(
                xtc, Wm1t, bm1, hbuf, mu2 + (size_t)mc * 16384,
                rs2 + (size_t)mc * 16384, S1m, S2m, nullptr);
            gemm128<48, HID_, E_, 2, 0, 0><<<dim3(E_ / 128, 128), 256, 0, stream>>>(
                hbuf, Wm2t, bm2, xtc, nullptr, nullptr, nullptr, nullptr, nullptr);
        }
        k4_out<<<dim3(P_ / 64, E_ / 32, B_), 256, 0, stream>>>(xt, (float*)d_out);
    }
}

// Round 17
// 518.017 us; speedup vs baseline: 1.2856x; 1.0056x over previous
//
#include <hip/hip_runtime.h>
#include <hip/hip_bf16.h>
#include <math.h>

// ---- problem dims ----
#define B_    16
#define E_    384
#define P_    4096
#define NW_   64
#define S_    64
#define H_    12
#define DH_   32
#define HID_  1536
#define T_    65536
#define SHIFT_ 4

typedef unsigned short ushort_t;
typedef __attribute__((ext_vector_type(8))) __bf16 b8;
typedef __attribute__((ext_vector_type(8))) ushort_t u8v;
typedef __attribute__((ext_vector_type(4))) float f4;
typedef __attribute__((ext_vector_type(4))) unsigned u32x4;

__device__ __forceinline__ float u2f(ushort_t u){
    return __uint_as_float(((unsigned)u) << 16);
}
__device__ __forceinline__ ushort_t f2u(float f){
    union { __hip_bfloat16 h; ushort_t u; } cv;
    cv.h = __float2bfloat16(f);
    return cv.u;
}
__device__ __forceinline__ unsigned pack2(float lo, float hi){
    return (unsigned)f2u(lo) | ((unsigned)f2u(hi) << 16);
}
// fast gelu: tanh-form via sigmoid, max abs err ~3e-4 (<< bf16 ulp here).
__device__ __forceinline__ float gelu_f(float v){
    const float y2 = v * (1.5957691216057308f + 0.0713548162726f * v * v);
    return v * __builtin_amdgcn_rcpf(1.f + __expf(-y2));
}

#define MFMA(a,b,c) __builtin_amdgcn_mfma_f32_16x16x32_bf16((a),(b),(c),0,0,0)

// async global->LDS, 16B per lane (lds dest must be uniform + lane*16)
#define GL2LDS(gp, lp) \
    __builtin_amdgcn_global_load_lds((const __attribute__((address_space(1))) void*)(gp), \
                                     (__attribute__((address_space(3))) void*)(lp), 16, 0, 0)

// window-order row m -> linear row p (shift+window inverse), chunk-local
template<int PERM>
__device__ __forceinline__ int rowmap(int m){
    if (PERM == 0) return m;
    const int bl = m >> 12, wn = (m >> 6) & 63, sd = m & 63;
    const int i_ = ((wn >> 3) << 3) + (sd >> 3);
    const int j_ = ((wn & 7) << 3) + (sd & 7);
    const int d1 = (i_ + SHIFT_) & 63;
    const int d2 = (j_ + SHIFT_) & 63;
    return (bl << 12) + (d1 << 6) + d2;
}

// =====================================================================
// prep_all bodies
// =====================================================================
__device__ void wt_body(int bx, int by, int tid,
    const float* __restrict__ src, ushort_t* __restrict__ dst, int K, int N,
    float scale, const float* __restrict__ gv)
{
    __shared__ float t[32][33];
    const int k0 = bx * 32, n0 = by * 32;
    const int c = tid & 31, r = tid >> 5;
    for (int rr = r; rr < 32; rr += 8)
        t[rr][c] = src[(size_t)(k0 + rr) * N + n0 + c];
    __syncthreads();
    const float gg = (gv ? gv[k0 + c] : 1.f) * scale;
    for (int rr = r; rr < 32; rr += 8)
        dst[(size_t)(n0 + rr) * K + k0 + c] = f2u(t[c][rr] * gg);
}

__device__ void lnfold_body(int bx, int tid,
    const float* __restrict__ W, const float* __restrict__ g,
    const float* __restrict__ bt, float scale, int N,
    float* __restrict__ S1, float* __restrict__ S2)
{
    __shared__ float r1[8][32], r2[8][32];
    const int c = tid & 31, ks = tid >> 5;
    const int n = bx * 32 + c;
    float s1 = 0.f, s2 = 0.f;
#pragma unroll
    for (int i = 0; i < 48; ++i){     // K = 384 = 8*48
        const int k = ks * 48 + i;
        const float w = W[(size_t)k * N + n];
        s1 += g[k] * w;
        s2 += bt[k] * w;
    }
    r1[ks][c] = s1; r2[ks][c] = s2;
    __syncthreads();
    if (tid < 32){
        float a = 0.f, b2 = 0.f;
#pragma unroll
        for (int j = 0; j < 8; ++j){ a += r1[j][tid]; b2 += r2[j][tid]; }
        S1[bx * 32 + tid] = a * scale;
        S2[bx * 32 + tid] = b2 * scale;
    }
}

// one launch for all weight transposes + LN folds + bias concat
__global__ __launch_bounds__(256) void prep_all(
    const float* Wq, const float* Wk, const float* Wv, const float* Wo,
    const float* Wm1, const float* Wm2,
    const float* ln1_g, const float* ln1_b,
    const float* ln2_g, const float* ln2_b,
    const float* bq, const float* bk, const float* bv,
    ushort_t* Wqkvt, ushort_t* Wot, ushort_t* Wm1t, ushort_t* Wm2t,
    float* S1q, float* S2q, float* S1m, float* S2m, float* bqkv)
{
    const float qscale = 0.17677669529663687f;
    const int id = blockIdx.x, tid = threadIdx.x;
    if (id < 144)       wt_body(id % 12, id / 12, tid, Wq, Wqkvt, E_, E_, qscale, ln1_g);
    else if (id < 288){ const int l = id - 144; wt_body(l % 12, l / 12, tid, Wk, Wqkvt + 384 * E_, E_, E_, 1.f, ln1_g); }
    else if (id < 432){ const int l = id - 288; wt_body(l % 12, l / 12, tid, Wv, Wqkvt + 768 * E_, E_, E_, 1.f, ln1_g); }
    else if (id < 576){ const int l = id - 432; wt_body(l % 12, l / 12, tid, Wo, Wot, E_, E_, 1.f, nullptr); }
    else if (id < 1152){ const int l = id - 576; wt_body(l % 12, l / 12, tid, Wm1, Wm1t, E_, HID_, 1.f, ln2_g); }
    else if (id < 1728){ const int l = id - 1152; wt_body(l % 48, l / 48, tid, Wm2, Wm2t, HID_, E_, 1.f, nullptr); }
    else if (id < 1740) lnfold_body(id - 1728, tid, Wq, ln1_g, ln1_b, qscale, E_, S1q, S2q);
    else if (id < 1752) lnfold_body(id - 1740, tid, Wk, ln1_g, ln1_b, 1.f, E_, S1q + 384, S2q + 384);
    else if (id < 1764) lnfold_body(id - 1752, tid, Wv, ln1_g, ln1_b, 1.f, E_, S1q + 768, S2q + 768);
    else if (id < 1812) lnfold_body(id - 1764, tid, Wm1, ln2_g, ln2_b, 1.f, HID_, S1m, S2m);
    else {
        const int i = (id - 1812) * 256 + tid;
        if (i < 1152){
            float v;
            if (i < 384)      v = bq[i] * qscale;
            else if (i < 768) v = bk[i - 384];
            else              v = bv[i - 768];
            bqkv[i] = v;
        }
    }
}

// =====================================================================
// K1: x (B,E,P) f32 -> xt bf16 (B,P,E), + LN1 stats in WINDOW order.
// =====================================================================
__global__ __launch_bounds__(256) void k1_ln_window(
    const float* __restrict__ x, ushort_t* __restrict__ xt,
    float* __restrict__ mu1w, float* __restrict__ rs1w)
{
    __shared__ ushort_t tile[64][E_ + 2];        // bf16, stride 386
    __shared__ float redS[4][64], redQ[4][64];
    const int b = blockIdx.y, p0 = blockIdx.x * 64, tid = threadIdx.x;

    {
        const int pq = tid & 15, e00 = tid >> 4;
        const float* xp = x + ((size_t)b * E_ + e00) * P_ + p0 + pq * 4;
        f4 v[24];
#pragma unroll
        for (int i = 0; i < 24; ++i)
            v[i] = *(const f4*)(xp + (size_t)(i * 16) * P_);
        float s0 = 0.f, s1 = 0.f, s2 = 0.f, s3 = 0.f;
        float q0 = 0.f, q1 = 0.f, q2 = 0.f, q3 = 0.f;
#pragma unroll
        for (int i = 0; i < 24; ++i){
            const int e = e00 + i * 16;
            tile[pq * 4 + 0][e] = f2u(v[i][0]);
            tile[pq * 4 + 1][e] = f2u(v[i][1]);
            tile[pq * 4 + 2][e] = f2u(v[i][2]);
            tile[pq * 4 + 3][e] = f2u(v[i][3]);
            s0 += v[i][0]; q0 += v[i][0] * v[i][0];
            s1 += v[i][1]; q1 += v[i][1] * v[i][1];
            s2 += v[i][2]; q2 += v[i][2] * v[i][2];
            s3 += v[i][3]; q3 += v[i][3] * v[i][3];
        }
        s0 += __shfl_xor(s0, 16); q0 += __shfl_xor(q0, 16);
        s1 += __shfl_xor(s1, 16); q1 += __shfl_xor(q1, 16);
        s2 += __shfl_xor(s2, 16); q2 += __shfl_xor(q2, 16);
        s3 += __shfl_xor(s3, 16); q3 += __shfl_xor(q3, 16);
        s0 += __shfl_xor(s0, 32); q0 += __shfl_xor(q0, 32);
        s1 += __shfl_xor(s1, 32); q1 += __shfl_xor(q1, 32);
        s2 += __shfl_xor(s2, 32); q2 += __shfl_xor(q2, 32);
        s3 += __shfl_xor(s3, 32); q3 += __shfl_xor(q3, 32);
        const int lane = tid & 63, wvi = tid >> 6;
        if (lane < 16){
            redS[wvi][pq * 4 + 0] = s0; redQ[wvi][pq * 4 + 0] = q0;
            redS[wvi][pq * 4 + 1] = s1; redQ[wvi][pq * 4 + 1] = q1;
            redS[wvi][pq * 4 + 2] = s2; redQ[wvi][pq * 4 + 2] = q2;
            redS[wvi][pq * 4 + 3] = s3; redQ[wvi][pq * 4 + 3] = q3;
        }
    }
    __syncthreads();
    if (tid < 64){
        const float s  = redS[0][tid] + redS[1][tid] + redS[2][tid] + redS[3][tid];
        const float ss = redQ[0][tid] + redQ[1][tid] + redQ[2][tid] + redQ[3][tid];
        const float mu = s / E_;
        const float rs = rsqrtf(ss / E_ - mu * mu + 1e-5f);
        const int p = p0 + tid;
        const int d1 = p >> 6, d2 = p & 63;
        const int i_ = (d1 + 64 - SHIFT_) & 63;
        const int j_ = (d2 + 64 - SHIFT_) & 63;
        const int wsd = ((((i_ >> 3) << 3) + (j_ >> 3)) << 6)
                      + ((i_ & 7) << 3) + (j_ & 7);
        mu1w[b * P_ + wsd] = mu;
        rs1w[b * P_ + wsd] = rs;
    }

    unsigned* xtu = (unsigned*)xt;
    for (int it = 0; it < 48; ++it){
        const int idx = it * 256 + tid;
        const int pj = idx / 192, ep = idx - pj * 192;
        xtu[((size_t)b * P_ + p0 + pj) * 192 + ep] = *(const unsigned*)&tile[pj][ep * 2];
    }
}

// =====================================================================
// gemm128: C = A[M][AS] @ Bm^T + epilogue, 128x128 tiles.
// Triple-buffered LDS, counted vmcnt(4), T2 both-sides swizzle,
// T5 setprio around MFMA cluster.
// MODE 0: store bf16 nt (qkv)  1: gelu, store bf16 (h; L2/L3-resident)
//      2: gelu + residual RMW  3: residual RMW + window-reverse (Wo)
//      4: gelu + residual (resid ptr) -> TRANSPOSED f32 out (kills k4)
// =====================================================================
template<int KST, int AS, int OS, int MODE, int LNF, int PERM>
__global__ __launch_bounds__(256, 3) void gemm128(
    const ushort_t* __restrict__ A, const ushort_t* __restrict__ Bm,
    const float* __restrict__ bias, ushort_t* __restrict__ out,
    const float* __restrict__ mu, const float* __restrict__ rs,
    const float* __restrict__ S1, const float* __restrict__ S2,
    const ushort_t* __restrict__ resid)
{
    __shared__ __align__(16) ushort_t lds[24576];   // 3 x (A 4096 + B 4096)
    const int tid = threadIdx.x, lane = tid & 63, wv = tid >> 6;
    const int l15 = lane & 15, l4 = lane >> 4;
    const int wr = wv >> 1, wc = wv & 1;

    // XCD-aware bijective remap (all grids have nwg % 8 == 0)
    const int gx = gridDim.x;
    const int nwg = gx * gridDim.y;
    const int d = blockIdx.y * gx + blockIdx.x;
    const int cpx = nwg >> 3;
    const int lb = (d & 7) * cpx + (d >> 3);
    const int n0 = (lb % gx) * 128;
    const size_t m0 = (size_t)(lb / gx) * 128;

    // per-thread staging source offsets; quad pre-swizzled: q_g = kq^((row>>1)&3)
    const int kq = tid & 3;
    const int xq = kq ^ ((tid >> 3) & 3);
    size_t aoff0, aoff1, boff0, boff1;
    {
        const int r0 = (int)m0 + (tid >> 2);
        aoff0 = (size_t)rowmap<PERM>(r0) * AS + xq * 8;
        aoff1 = (size_t)rowmap<PERM>(r0 + 64) * AS + xq * 8;
        const int nr = n0 + (tid >> 2);
        boff0 = (size_t)nr * (KST * 32) + xq * 8;
        boff1 = boff0 + (size_t)64 * (KST * 32);
    }

#define STG(cur, k0) do { \
        ushort_t* dst_ = lds + (cur) * 8192; \
        GL2LDS(A + aoff0 + (k0), dst_ + tid * 8); \
        GL2LDS(A + aoff1 + (k0), dst_ + (256 + tid) * 8); \
        GL2LDS(Bm + boff0 + (k0), dst_ + 4096 + tid * 8); \
        GL2LDS(Bm + boff1 + (k0), dst_ + 4096 + (256 + tid) * 8); \
    } while (0)

    f4 acc[4][4];
#pragma unroll
    for (int i = 0; i < 4; ++i)
#pragma unroll
        for (int j = 0; j < 4; ++j) acc[i][j] = (f4){0.f, 0.f, 0.f, 0.f};

    const int rq = (l4 ^ ((l15 >> 1) & 3)) * 8;

    STG(0, 0);
    STG(1, 32);
    for (int ks = 0; ks < KST; ++ks){
        if (ks < KST - 1) asm volatile("s_waitcnt vmcnt(4)" ::: "memory");
        else              asm volatile("s_waitcnt vmcnt(0)" ::: "memory");
        __builtin_amdgcn_s_barrier();
        asm volatile("" ::: "memory");
        if (ks + 2 < KST) STG((ks + 2) % 3, (ks + 2) * 32);
        asm volatile("" ::: "memory");
        const ushort_t* Al = lds + (ks % 3) * 8192;
        const ushort_t* Bl = Al + 4096;
        b8 ax[4], aw[4];
#pragma unroll
        for (int f = 0; f < 4; ++f){
            ax[f] = *(const b8*)(Al + (wr * 64 + f * 16 + l15) * 32 + rq);
            aw[f] = *(const b8*)(Bl + (wc * 64 + f * 16 + l15) * 32 + rq);
        }
        __builtin_amdgcn_s_setprio(1);
#pragma unroll
        for (int fm = 0; fm < 4; ++fm)
#pragma unroll
            for (int fn = 0; fn < 4; ++fn)
                acc[fm][fn] = MFMA(aw[fn], ax[fm], acc[fm][fn]);
        __builtin_amdgcn_s_setprio(0);
    }
#undef STG

    if (MODE == 4){
        // gelu + residual (f32) -> LDS transpose [128 e][36 p] -> f32 out
        float* Tf = (float*)lds;
        float* outf = (float*)out;          // chunk base
#pragma unroll
        for (int rg = 0; rg < 4; ++rg){
            __syncthreads();
            if (wr == (rg >> 1)){
#pragma unroll
                for (int f2h = 0; f2h < 2; ++f2h){
                    const int fm = (rg & 1) * 2 + f2h;
                    const int m5 = f2h * 16 + l15;
                    const int grow = (int)m0 + rg * 32 + m5;
#pragma unroll
                    for (int fn = 0; fn < 4; ++fn){
                        const f4 v = acc[fm][fn];
                        const int nc = wc * 64 + fn * 16 + l4 * 4;
                        const f4 bb = *(const f4*)(bias + n0 + nc);
                        const uint2 ov = *(const uint2*)(resid + (size_t)grow * E_ + n0 + nc);
                        Tf[(nc + 0) * 36 + m5] = u2f((ushort_t)ov.x)         + gelu_f(v[0] + bb[0]);
                        Tf[(nc + 1) * 36 + m5] = u2f((ushort_t)(ov.x >> 16)) + gelu_f(v[1] + bb[1]);
                        Tf[(nc + 2) * 36 + m5] = u2f((ushort_t)ov.y)         + gelu_f(v[2] + bb[2]);
                        Tf[(nc + 3) * 36 + m5] = u2f((ushort_t)(ov.y >> 16)) + gelu_f(v[3] + bb[3]);
                    }
                }
            }
            __syncthreads();
            {
                // per instruction: lane quad covers 64B contiguous p-range
                const int growb = (int)m0 + rg * 32;
                const int bl = growb >> 12, p12 = growb & 4095;
                const int po = (tid & 3) * 4;
#pragma unroll
                for (int eh = 0; eh < 2; ++eh){
                    const int e = eh * 64 + (tid >> 2);
                    float* op = outf + ((size_t)bl * E_ + n0 + e) * P_ + p12 + po;
                    const float* tp = &Tf[e * 36 + po];
                    __builtin_nontemporal_store(*(const f4*)tp, (f4*)op);
                    __builtin_nontemporal_store(*(const f4*)(tp + 16), (f4*)(op + 16));
                }
            }
        }
        return;
    }

    // epilogue via per-wave LDS bounce [32][72] -> coalesced b128
    ushort_t* bounce = lds + wv * 2304;
    const int l8r = lane >> 3, l8c = lane & 7;
#pragma unroll
    for (int hh = 0; hh < 2; ++hh){
#pragma unroll
        for (int f2 = 0; f2 < 2; ++f2){
            const int fm = hh * 2 + f2;
            float mur = 0.f, rsr = 1.f;
            if (LNF){
                const int gm = (int)m0 + wr * 64 + fm * 16 + l15;
                mur = mu[gm]; rsr = rs[gm];
            }
#pragma unroll
            for (int fn = 0; fn < 4; ++fn){
                const f4 v = acc[fm][fn];
                const int nc = n0 + wc * 64 + fn * 16 + l4 * 4;
                const f4 bb = *(const f4*)(bias + nc);
                f4 w;
                if (LNF){
                    const f4 s1 = *(const f4*)(S1 + nc);
                    const f4 s2 = *(const f4*)(S2 + nc);
#pragma unroll
                    for (int r = 0; r < 4; ++r)
                        w[r] = rsr * v[r] - rsr * mur * s1[r] + s2[r] + bb[r];
                } else {
#pragma unroll
                    for (int r = 0; r < 4; ++r) w[r] = v[r] + bb[r];
                }
                uint2 pk;
                if (MODE == 1 || MODE == 2){
                    pk.x = pack2(gelu_f(w[0]), gelu_f(w[1]));
                    pk.y = pack2(gelu_f(w[2]), gelu_f(w[3]));
                } else {
                    pk.x = pack2(w[0], w[1]);
                    pk.y = pack2(w[2], w[3]);
                }
                *(uint2*)(bounce + (f2 * 16 + l15) * 72 + fn * 16 + l4 * 4) = pk;
            }
        }
#pragma unroll
        for (int i = 0; i < 4; ++i){
            const int br = i * 8 + l8r;
            const int grow = (int)m0 + wr * 64 + hh * 32 + br;
            const b8 yv = *(const b8*)(bounce + br * 72 + l8c * 8);
            size_t orow;
            if (MODE == 3){
                orow = (size_t)rowmap<1>(grow);
            } else {
                orow = (size_t)grow;
            }
            ushort_t* px = out + orow * OS + n0 + wc * 64 + l8c * 8;
            if (MODE >= 2){
                const b8 ov = *(const b8*)px;
                union { b8 v; unsigned u[4]; } o;
#pragma unroll
                for (int j = 0; j < 4; ++j)
                    o.u[j] = pack2((float)ov[2 * j] + (float)yv[2 * j],
                                   (float)ov[2 * j + 1] + (float)yv[2 * j + 1]);
                *(b8*)px = o.v;
            } else if (MODE == 0){
                union { b8 v; u32x4 q; } t; t.v = yv;
                __builtin_nontemporal_store(t.q, (u32x4*)px);
            } else {
                // MODE 1: h consumed by the NEXT launch -> keep in L2
                *(b8*)px = yv;
            }
        }
    }
}

// =====================================================================
// K2b: attention core. qkv [rows][1152] chunk-local (q|k|v, q scaled),
// block = (window, batch-in-chunk, head-group of 4). z [rows][384] out.
// r17: mask hoisted to registers (head-invariant), __expf, rcp for 1/s.
// =====================================================================
__global__ __launch_bounds__(256) void k2b_attn(
    const ushort_t* __restrict__ qkv,
    const float* __restrict__ pb, const float* __restrict__ mk,
    ushort_t* __restrict__ z)
{
    __shared__ __align__(16) ushort_t q_lds[64 * 32];
    __shared__ __align__(16) ushort_t k_lds[64 * 32];
    __shared__ __align__(16) ushort_t vt_lds[32 * 72];
    __shared__ __align__(16) ushort_t P_lds[64 * 72];

    const int w = blockIdx.x, bl = blockIdx.y, hz = blockIdx.z;
    const int tid = threadIdx.x, lane = tid & 63, wv = tid >> 6;
    const int l15 = lane & 15, l4 = lane >> 4;
    const int rowbase = (bl * NW_ + w) * S_;

    const int srow = tid >> 2, sqp = tid & 3;
    const int sfq = sqp ^ ((srow >> 1) & 3);
    const ushort_t* gql = qkv + (size_t)(rowbase + srow) * 1152 + sfq * 8;
    const ushort_t* gvl = qkv + (size_t)(rowbase + srow) * 1152 + 768 + sqp * 8;

    // hoist head-invariant mask values: mk[(w, sw, t)], sw=wv*16+l4*4+r, t=nt*16+l15
    f4 mkr[4];
#pragma unroll
    for (int nt = 0; nt < 4; ++nt){
        const int t = nt * 16 + l15;
#pragma unroll
        for (int r = 0; r < 4; ++r){
            const int sw = wv * 16 + l4 * 4 + r;
            mkr[nt][r] = mk[((size_t)w * S_ + sw) * S_ + t];
        }
    }

    for (int hi = 0; hi < 4; ++hi){
        const int h = hz * 4 + hi;
        const int hb = h * 32;
        GL2LDS(gql + hb, q_lds + tid * 8);
        GL2LDS(gql + 384 + hb, k_lds + tid * 8);
        {
            const u8v vv = *(const u8v*)(gvl + hb);
#pragma unroll
            for (int j = 0; j < 8; ++j)
                vt_lds[(sqp * 8 + j) * 72 + srow] = vv[j];
        }
        __syncthreads();

        {
            const int qr = wv * 16 + l15;
            const int uq = qr * 4 + (l4 ^ ((qr >> 1) & 3));
            const b8 qfrag = *(const b8*)(&q_lds[uq * 8]);
            f4 sacc[4];
#pragma unroll
            for (int nt = 0; nt < 4; ++nt){
                const int kr = nt * 16 + l15;
                const int uk = kr * 4 + (l4 ^ ((kr >> 1) & 3));
                const b8 kfrag = *(const b8*)(&k_lds[uk * 8]);
                f4 c = (f4){0.f, 0.f, 0.f, 0.f};
                c = MFMA(qfrag, kfrag, c);
                const int t = nt * 16 + l15;
#pragma unroll
                for (int r = 0; r < 4; ++r){
                    const int sw = wv * 16 + l4 * 4 + r;
                    c[r] += pb[((size_t)h * S_ + sw) * S_ + t] + mkr[nt][r];
                }
                sacc[nt] = c;
            }
#pragma unroll
            for (int r = 0; r < 4; ++r){
                float m = fmaxf(fmaxf(sacc[0][r], sacc[1][r]),
                                fmaxf(sacc[2][r], sacc[3][r]));
                m = fmaxf(m, __shfl_xor(m, 1));
                m = fmaxf(m, __shfl_xor(m, 2));
                m = fmaxf(m, __shfl_xor(m, 4));
                m = fmaxf(m, __shfl_xor(m, 8));
                const float e0 = __expf(sacc[0][r] - m), e1 = __expf(sacc[1][r] - m);
                const float e2 = __expf(sacc[2][r] - m), e3 = __expf(sacc[3][r] - m);
                float s = e0 + e1 + e2 + e3;
                s += __shfl_xor(s, 1); s += __shfl_xor(s, 2);
                s += __shfl_xor(s, 4); s += __shfl_xor(s, 8);
                const float inv = __builtin_amdgcn_rcpf(s);
                const int row = wv * 16 + l4 * 4 + r;
                P_lds[row * 72 +      l15] = f2u(e0 * inv);
                P_lds[row * 72 + 16 + l15] = f2u(e1 * inv);
                P_lds[row * 72 + 32 + l15] = f2u(e2 * inv);
                P_lds[row * 72 + 48 + l15] = f2u(e3 * inv);
            }
        }

        {
            f4 zacc[2];
#pragma unroll
            for (int nt = 0; nt < 2; ++nt) zacc[nt] = (f4){0.f, 0.f, 0.f, 0.f};
#pragma unroll
            for (int kb = 0; kb < 2; ++kb){
                const b8 pfrag = *(const b8*)(&P_lds[(wv * 16 + l15) * 72 + kb * 32 + l4 * 8]);
#pragma unroll
                for (int nt = 0; nt < 2; ++nt){
                    const b8 vfrag = *(const b8*)(&vt_lds[(nt * 16 + l15) * 72 + kb * 32 + l4 * 8]);
                    zacc[nt] = MFMA(pfrag, vfrag, zacc[nt]);
                }
            }
#pragma unroll
            for (int nt = 0; nt < 2; ++nt)
#pragma unroll
                for (int r = 0; r < 4; ++r){
                    const int row = wv * 16 + l4 * 4 + r;
                    z[(size_t)(rowbase + row) * E_ + hb + nt * 16 + l15] = f2u(zacc[nt][r]);
                }
        }
        __syncthreads();
    }
}

// =====================================================================
// LN2 stats only (LN2 itself folded into mlp gemm1)
// =====================================================================
__global__ __launch_bounds__(256) void ln2_stats(
    const ushort_t* __restrict__ xt, float* __restrict__ mu2, float* __restrict__ rs2)
{
    const int tid = threadIdx.x;
    const int lr = blockIdx.x * 64 + (tid >> 2), q = tid & 3;
    const ushort_t* rp = xt + (size_t)lr * E_;
    float s = 0.f, ss = 0.f;
#pragma unroll
    for (int i = 0; i < 12; ++i){
        const b8 v = *(const b8*)(rp + q * 8 + i * 32);
#pragma unroll
        for (int j = 0; j < 8; ++j){ const float f = (float)v[j]; s += f; ss += f * f; }
    }
    s += __shfl_xor(s, 1); ss += __shfl_xor(ss, 1);
    s += __shfl_xor(s, 2); ss += __shfl_xor(ss, 2);
    if (q == 0){
        const float m = s * (1.f / E_);
        mu2[lr] = m;
        rs2[lr] = rsqrtf(ss * (1.f / E_) - m * m + 1e-5f);
    }
}

// =====================================================================
// K4 (fallback when ws too small): xt bf16 -> out f32 (B,E,P)
// =====================================================================
__global__ __launch_bounds__(256) void k4_out(
    const ushort_t* __restrict__ xt, float* __restrict__ out)
{
    __shared__ float tile[32][68];
    const int b = blockIdx.z, p0 = blockIdx.x * 64, e0 = blockIdx.y * 32;
    const int tid = threadIdx.x;
    {
        const int r = tid >> 2, c = tid & 3;
        const u8v v = *(const u8v*)(xt + ((size_t)b * P_ + p0 + r) * E_ + e0 + c * 8);
#pragma unroll
        for (int j = 0; j < 8; ++j)
            tile[c * 8 + j][r] = u2f(v[j]);
    }
    __syncthreads();
    {
        const int er = tid >> 3, pc = tid & 7;
        float* op = out + ((size_t)b * E_ + e0 + er) * P_ + p0 + pc * 8;
        const f4 v0 = *(const f4*)&tile[er][pc * 8];
        const f4 v1 = *(const f4*)&tile[er][pc * 8 + 4];
        __builtin_nontemporal_store(v0, (f4*)op);
        __builtin_nontemporal_store(v1, (f4*)(op + 4));
    }
}

// =====================================================================
extern "C" void kernel_launch(void* const* d_in, const int* in_sizes, int n_in,
                              void* d_out, int out_size, void* d_ws, size_t ws_size,
                              hipStream_t stream)
{
    const float* x      = (const float*)d_in[0];
    const float* mask   = (const float*)d_in[1];
    const float* ln1_g  = (const float*)d_in[2];
    const float* ln1_b  = (const float*)d_in[3];
    const float* Wq     = (const float*)d_in[4];
    const float* bq     = (const float*)d_in[5];
    const float* Wk     = (const float*)d_in[6];
    const float* bk     = (const float*)d_in[7];
    const float* Wv     = (const float*)d_in[8];
    const float* bv     = (const float*)d_in[9];
    const float* Wo     = (const float*)d_in[10];
    const float* bo     = (const float*)d_in[11];
    const float* pos_b  = (const float*)d_in[12];
    const float* ln2_g  = (const float*)d_in[13];
    const float* ln2_b  = (const float*)d_in[14];
    const float* Wm1    = (const float*)d_in[15];
    const float* bm1    = (const float*)d_in[16];
    const float* Wm2    = (const float*)d_in[17];
    const float* bm2    = (const float*)d_in[18];

    ushort_t* xt = (ushort_t*)d_ws;
    const bool bigws = ws_size >= (size_t)103022592;
    ushort_t* scratch = (ushort_t*)d_out;

    if (bigws){
        // ---- bigws layout (audited r15/r16) ----
        ushort_t* qkvb  = scratch;
        ushort_t* Wqkvt = scratch + 37748736;
        ushort_t* Wot   = Wqkvt + 1152 * E_;
        float*    bqkv  = (float*)(scratch + 38338560);
        float*    S1q   = (float*)(scratch + 38340864);
        float*    S2q   = (float*)(scratch + 38343168);
        float*    S1m   = (float*)(scratch + 38345472);
        float*    S2m   = (float*)(scratch + 38348544);
        float*    mu1w  = (float*)(scratch + 38351616);
        float*    rs1w  = (float*)(scratch + 38482688);
        float*    mu2   = (float*)(scratch + 38613760);
        float*    rs2   = (float*)(scratch + 38744832);
        ushort_t* zb    = xt + 25165824;
        ushort_t* hbuf  = xt + 25165824;
        ushort_t* Wm1t  = xt + 50331648;
        ushort_t* Wm2t  = Wm1t + E_ * HID_;

        prep_all<<<1817, 256, 0, stream>>>(Wq, Wk, Wv, Wo, Wm1, Wm2,
            ln1_g, ln1_b, ln2_g, ln2_b, bq, bk, bv,
            Wqkvt, Wot, Wm1t, Wm2t, S1q, S2q, S1m, S2m, bqkv);

        k1_ln_window<<<dim3(P_ / 64, B_), 256, 0, stream>>>(x, xt, mu1w, rs1w);

        // ---- attention phase: 2 chunks of 8 batches (32768 rows) ----
        for (int mc = 0; mc < 2; ++mc){
            ushort_t* xtc = xt + (size_t)mc * 32768 * E_;
            gemm128<12, E_, 1152, 0, 1, 1><<<dim3(9, 256), 256, 0, stream>>>(
                xtc, Wqkvt, bqkv, qkvb, mu1w + (size_t)mc * 32768,
                rs1w + (size_t)mc * 32768, S1q, S2q, nullptr);
            k2b_attn<<<dim3(NW_, 8, 3), 256, 0, stream>>>(qkvb, pos_b, mask, zb);
            gemm128<12, E_, E_, 3, 0, 0><<<dim3(3, 256), 256, 0, stream>>>(
                zb, Wot, bo, xtc, nullptr, nullptr, nullptr, nullptr, nullptr);
        }

        // ---- MLP phase: 4 chunks of 16384 rows (hbuf capacity bound) ----
        ln2_stats<<<T_ / 64, 256, 0, stream>>>(xt, mu2, rs2);
        for (int mc = 0; mc < 4; ++mc){
            ushort_t* xtc = xt + (size_t)mc * 16384 * E_;
            gemm128<12, E_, HID_, 1, 1, 0><<<dim3(HID_ / 128, 128), 256, 0, stream>>>(
                xtc, Wm1t, bm1, hbuf, mu2 + (size_t)mc * 16384,
                rs2 + (size_t)mc * 16384, S1m, S2m, nullptr);
            ushort_t* outc = (ushort_t*)((float*)d_out + (size_t)(mc * 4) * E_ * P_);
            gemm128<48, HID_, E_, 4, 0, 0><<<dim3(E_ / 128, 128), 256, 0, stream>>>(
                hbuf, Wm2t, bm2, outc, nullptr, nullptr, nullptr, nullptr, xtc);
        }
    } else {
        // ---- fallback: 4-chunk attention, MODE2 + k4 ----
        ushort_t* zb    = scratch;
        ushort_t* hbuf  = scratch;
        ushort_t* Wqkvt = scratch + 25165824;
        ushort_t* Wot   = Wqkvt + 1152 * E_;
        ushort_t* Wm1t  = Wot + E_ * E_;
        ushort_t* Wm2t  = Wm1t + E_ * HID_;
        ushort_t* qkvb  = scratch + 26935296;
        float*    bqkv  = (float*)(scratch + 45809664);
        float*    S1q   = (float*)(scratch + 45811968);
        float*    S2q   = (float*)(scratch + 45814272);
        float*    S1m   = (float*)(scratch + 45816576);
        float*    S2m   = (float*)(scratch + 45819648);
        float*    mu1w  = (float*)(scratch + 45822720);
        float*    rs1w  = (float*)(scratch + 45953792);
        float*    mu2   = (float*)(scratch + 46084864);
        float*    rs2   = (float*)(scratch + 46215936);

        prep_all<<<1817, 256, 0, stream>>>(Wq, Wk, Wv, Wo, Wm1, Wm2,
            ln1_g, ln1_b, ln2_g, ln2_b, bq, bk, bv,
            Wqkvt, Wot, Wm1t, Wm2t, S1q, S2q, S1m, S2m, bqkv);

        k1_ln_window<<<dim3(P_ / 64, B_), 256, 0, stream>>>(x, xt, mu1w, rs1w);

        for (int mc = 0; mc < 4; ++mc){
            ushort_t* xtc = xt + (size_t)mc * 16384 * E_;
            gemm128<12, E_, 1152, 0, 1, 1><<<dim3(9, 128), 256, 0, stream>>>(
                xtc, Wqkvt, bqkv, qkvb, mu1w + (size_t)mc * 16384,
                rs1w + (size_t)mc * 16384, S1q, S2q, nullptr);
            k2b_attn<<<dim3(NW_, 4, 3), 256, 0, stream>>>(qkvb, pos_b, mask, zb);
            gemm128<12, E_, E_, 3, 0, 0><<<dim3(3, 128), 256, 0, stream>>>(
                zb, Wot, bo, xtc, nullptr, nullptr, nullptr, nullptr, nullptr);
        }

        ln2_stats<<<T_ / 64, 256, 0, stream>>>(xt, mu2, rs2);
        for (int mc = 0; mc < 4; ++mc){
            ushort_t* xtc = xt + (size_t)mc * 16384 * E_;
            gemm128<12, E_, HID_, 1, 1, 0><<<dim3(HID_ / 128, 128), 256, 0, stream>>>(
                xtc, Wm1t, bm1, hbuf, mu2 + (size_t)mc * 16384,
                rs2 + (size_t)mc * 16384, S1m, S2m, nullptr);
            gemm128<48, HID_, E_, 2, 0, 0><<<dim3(E_ / 128, 128), 256, 0, stream>>>(
                hbuf, Wm2t, bm2, xtc, nullptr, nullptr, nullptr, nullptr, nullptr);
        }
        k4_out<<<dim3(P_ / 64, E_ / 32, B_), 256, 0, stream>>>(xt, (float*)d_out);
    }
}